// Round 1
// baseline (2706.641 us; speedup 1.0000x reference)
//
#include <hip/hip_runtime.h>
#include <cmath>

// B=4, N=1024, DIM=1024, H=16, DH=64, M=16, QK_SCALE=10
#define M_ 16
#define TJ 256
#define TJP 257

// ---------------- GEMM: C[M x N] = A[M x K] @ B[K x N], fp32, 64x64 tile ----
__global__ __launch_bounds__(256)
void gemm_f32(const float* __restrict__ A, const float* __restrict__ Bm,
              float* __restrict__ C, int M, int N, int K)
{
  __shared__ float As[16][68];   // [k][m], stride 68 keeps float4 alignment
  __shared__ float Bs[16][68];   // [k][n]
  const int t = threadIdx.x;
  const int tx = t & 15, ty = t >> 4;
  const int row0 = blockIdx.y * 64, col0 = blockIdx.x * 64;
  float acc[4][4];
#pragma unroll
  for (int i = 0; i < 4; ++i)
#pragma unroll
    for (int j = 0; j < 4; ++j) acc[i][j] = 0.f;

  for (int kk = 0; kk < K; kk += 16) {
#pragma unroll
    for (int q = 0; q < 4; ++q) {
      int idx = t + q * 256;
      int c = idx & 15, r = idx >> 4;
      As[c][r] = A[(size_t)(row0 + r) * K + kk + c];
    }
#pragma unroll
    for (int q = 0; q < 4; ++q) {
      int idx = t + q * 256;
      int cb = idx & 63, rb = idx >> 6;
      int col = col0 + cb;
      Bs[rb][cb] = (col < N) ? Bm[(size_t)(kk + rb) * N + col] : 0.f;
    }
    __syncthreads();
#pragma unroll
    for (int k2 = 0; k2 < 16; ++k2) {
      float4 a4 = *(const float4*)&As[k2][ty << 2];
      float4 b4 = *(const float4*)&Bs[k2][tx << 2];
      float a[4] = {a4.x, a4.y, a4.z, a4.w};
      float b[4] = {b4.x, b4.y, b4.z, b4.w};
#pragma unroll
      for (int i = 0; i < 4; ++i)
#pragma unroll
        for (int j = 0; j < 4; ++j) acc[i][j] += a[i] * b[j];
    }
    __syncthreads();
  }
#pragma unroll
  for (int i = 0; i < 4; ++i) {
    int row = row0 + (ty << 2) + i;
#pragma unroll
    for (int j = 0; j < 4; ++j) {
      int col = col0 + (tx << 2) + j;
      if (col < N) C[(size_t)row * N + col] = acc[i][j];
    }
  }
}

// ------------- q/k postprocess: in-place l2norm * scale, then rope ----------
// layout [B,N,H,DH]; one wave (64 lanes) per (b,n,h) row. grid*256 == rows*64.
__global__ __launch_bounds__(256)
void qk_post(float* __restrict__ qk, const float* __restrict__ scale,
             const float* __restrict__ freqs)
{
  int gid = blockIdx.x * 256 + threadIdx.x;
  int d = gid & 63;
  int row = gid >> 6;            // (b*N+n)*H + h
  int h = row & 15;
  int n = (row >> 4) & 1023;
  float v = qk[gid];
  float ss = v * v;
#pragma unroll
  for (int off = 32; off; off >>= 1) ss += __shfl_xor(ss, off);
  v = v / fmaxf(sqrtf(ss), 1e-12f) * scale[(h << 6) + d];
  float f = freqs[(n << 6) + d];
  float other = __shfl_xor(v, 1);
  float rot = (d & 1) ? other : -other;   // even: -x[d+1], odd: x[d-1]
  qk[gid] = v * cosf(f) + rot * sinf(f);
}

// ------------- mem_k: l2norm * k_scale (no rope). total = H*M*64 = 16384 ----
__global__ __launch_bounds__(256)
void memk_post(const float* __restrict__ mem_k, const float* __restrict__ k_scale,
               float* __restrict__ mk)
{
  int gid = blockIdx.x * 256 + threadIdx.x;
  int d = gid & 63;
  int row = gid >> 6;            // h*M + m
  int h = row >> 4;
  float v = mem_k[gid];
  float ss = v * v;
#pragma unroll
  for (int off = 32; off; off >>= 1) ss += __shfl_xor(ss, off);
  mk[gid] = v / fmaxf(sqrtf(ss), 1e-12f) * k_scale[(h << 6) + d];
}

// ------------- sigmoid(x + bias[idx & mask]) in place -----------------------
__global__ __launch_bounds__(256)
void sigmoid_bias(float* __restrict__ x, const float* __restrict__ bias,
                  int n, int mask)
{
  int idx = blockIdx.x * 256 + threadIdx.x;
  if (idx < n) {
    float v = x[idx] + bias[idx & mask];
    x[idx] = 1.f / (1.f + __expf(-v));
  }
}

// ------------- fused attention with talking heads ---------------------------
// One block per (b,i). Two passes over j-tiles (stats, then PV) since W_post
// mixes *normalized* probs across heads (needs final l_g before PV).
__device__ __forceinline__ void fill_tile(float* __restrict__ sT, const float4 qv[4],
    const float* __restrict__ k_lin, const float* __restrict__ mkbuf,
    int b, int base, int tc, int lane, int w)
{
  const int h = lane >> 2, part = lane & 3;   // 16 heads x 4 16-dim chunks
  for (int jj = w; jj < tc; jj += 4) {        // wave-uniform loop
    const int j = base + jj;
    const float4* k4 = (j < M_)
      ? (const float4*)(mkbuf + (((h << 4) + j) << 6) + (part << 4))
      : (const float4*)(k_lin + ((size_t)((b << 10) + j - M_) << 10) + (lane << 4));
    float4 ka = k4[0], kb = k4[1], kc = k4[2], kd = k4[3];
    float acc = qv[0].x * ka.x + qv[0].y * ka.y + qv[0].z * ka.z + qv[0].w * ka.w
              + qv[1].x * kb.x + qv[1].y * kb.y + qv[1].z * kb.z + qv[1].w * kb.w
              + qv[2].x * kc.x + qv[2].y * kc.y + qv[2].z * kc.z + qv[2].w * kc.w
              + qv[3].x * kd.x + qv[3].y * kd.y + qv[3].z * kd.z + qv[3].w * kd.w;
    acc += __shfl_xor(acc, 1);
    acc += __shfl_xor(acc, 2);
    if (part == 0) sT[h * TJP + jj] = acc;    // raw (x10-scaled) dot
  }
}

__device__ __forceinline__ void mix_pre(const float* __restrict__ sT,
                                        const float* __restrict__ sWpre,
                                        int t, float* __restrict__ m)
{
  float c[16];
#pragma unroll
  for (int hh = 0; hh < 16; ++hh) c[hh] = sT[hh * TJP + t];
#pragma unroll
  for (int g = 0; g < 16; ++g) {
    float s = 0.f;
#pragma unroll
    for (int hh = 0; hh < 16; ++hh) s += sWpre[(g << 4) + hh] * c[hh];
    m[g] = s;
  }
}

__global__ __launch_bounds__(256)
void attn_fused(const float* __restrict__ q_lin, const float* __restrict__ k_lin,
                const float* __restrict__ v_lin, const float* __restrict__ mkbuf,
                const float* __restrict__ mem_v, const float* __restrict__ W_pre,
                const float* __restrict__ W_post, const float* __restrict__ hgate,
                const float* __restrict__ vgate, float* __restrict__ attn_out)
{
  __shared__ float sT[16 * TJP];
  __shared__ float sWpre[256], sWpost[256];
  __shared__ float sM[16], sL[16], sIL[16];

  const int t = threadIdx.x;
  const int lane = t & 63, w = t >> 6;
  const int bid = blockIdx.x;
  const int b = bid >> 10, i = bid & 1023;
  const int jmax = i + M_ + 1;               // causal: kpos <= i + M

  sWpre[t] = W_pre[t];
  sWpost[t] = W_post[t];
  if (t < 16) { sM[t] = -1e30f; sL[t] = 0.f; }

  // q fragment: lane holds q[h=lane>>2, d=(lane&3)*16 .. +15], QK_SCALE folded
  const float* qrow = q_lin + ((size_t)bid << 10);
  float4 qv[4];
#pragma unroll
  for (int u = 0; u < 4; ++u) {
    float4 qq = ((const float4*)qrow)[(lane << 2) + u];
    qq.x *= 10.f; qq.y *= 10.f; qq.z *= 10.f; qq.w *= 10.f;
    qv[u] = qq;
  }
  __syncthreads();

  // ---- pass 1: online stats (m_g, l_g) over W_pre-mixed logits ----
  for (int base = 0; base < jmax; base += TJ) {
    const int tc = min(TJ, jmax - base);
    fill_tile(sT, qv, k_lin, mkbuf, b, base, tc, lane, w);
    __syncthreads();
    if (t < tc) {
      float m[16];
      mix_pre(sT, sWpre, t, m);
#pragma unroll
      for (int g = 0; g < 16; ++g) sT[g * TJP + t] = m[g];
    }
    __syncthreads();
#pragma unroll
    for (int gg = 0; gg < 4; ++gg) {         // wave w owns rows w*4 .. w*4+3
      int g = (w << 2) + gg;
      float vmax = -1e30f;
      for (int jt = lane; jt < tc; jt += 64) vmax = fmaxf(vmax, sT[g * TJP + jt]);
#pragma unroll
      for (int off = 32; off; off >>= 1) vmax = fmaxf(vmax, __shfl_xor(vmax, off));
      float mold = sM[g];
      float mnew = fmaxf(mold, vmax);
      float s = 0.f;
      for (int jt = lane; jt < tc; jt += 64) s += __expf(sT[g * TJP + jt] - mnew);
#pragma unroll
      for (int off = 32; off; off >>= 1) s += __shfl_xor(s, off);
      if (lane == 0) { sL[g] = sL[g] * __expf(mold - mnew) + s; sM[g] = mnew; }
    }
    __syncthreads();
  }
  if (t < 16) sIL[t] = 1.f / sL[t];
  __syncthreads();

  // ---- pass 2: recompute logits, form W_post-mixed probs, accumulate PV ----
  const int gp = t >> 4, cc = t & 15;        // PV: 16 heads x 16 dim-quads
  float4 vacc = make_float4(0.f, 0.f, 0.f, 0.f);
  for (int base = 0; base < jmax; base += TJ) {
    const int tc = min(TJ, jmax - base);
    fill_tile(sT, qv, k_lin, mkbuf, b, base, tc, lane, w);
    __syncthreads();
    if (t < tc) {
      float m[16];
      mix_pre(sT, sWpre, t, m);
      float e[16];
#pragma unroll
      for (int g = 0; g < 16; ++g) e[g] = __expf(m[g] - sM[g]) * sIL[g];
#pragma unroll
      for (int g2 = 0; g2 < 16; ++g2) {
        float s = 0.f;
#pragma unroll
        for (int g = 0; g < 16; ++g) s += sWpost[(g2 << 4) + g] * e[g];
        sT[g2 * TJP + t] = s;                // p2[g2][col]
      }
    }
    __syncthreads();
#pragma unroll 4
    for (int jt = 0; jt < tc; ++jt) {
      int j = base + jt;
      float p = sT[gp * TJP + jt];
      const float4* vr = (j < M_)
        ? (const float4*)(mem_v + (((gp << 4) + j) << 6) + (cc << 2))
        : (const float4*)(v_lin + ((size_t)((b << 10) + j - M_) << 10) + (gp << 6) + (cc << 2));
      float4 vv = *vr;
      vacc.x += p * vv.x; vacc.y += p * vv.y; vacc.z += p * vv.z; vacc.w += p * vv.w;
    }
    __syncthreads();
  }
  float hg = hgate[(bid << 4) + gp];
  const float4 vg = *(const float4*)(vgate + ((size_t)bid << 10) + (gp << 6) + (cc << 2));
  float4 o;
  o.x = vacc.x * hg * vg.x;
  o.y = vacc.y * hg * vg.y;
  o.z = vacc.z * hg * vg.z;
  o.w = vacc.w * hg * vg.w;
  *(float4*)(attn_out + ((size_t)bid << 10) + (gp << 6) + (cc << 2)) = o;
}

extern "C" void kernel_launch(void* const* d_in, const int* in_sizes, int n_in,
                              void* d_out, int out_size, void* d_ws, size_t ws_size,
                              hipStream_t stream)
{
  const float* x       = (const float*)d_in[0];
  const float* freqs   = (const float*)d_in[1];
  const float* Wq      = (const float*)d_in[2];
  const float* Wk      = (const float*)d_in[3];
  const float* Wv      = (const float*)d_in[4];
  const float* q_scale = (const float*)d_in[5];
  const float* k_scale = (const float*)d_in[6];
  const float* mem_k   = (const float*)d_in[7];
  const float* mem_v   = (const float*)d_in[8];
  const float* W_pre   = (const float*)d_in[9];
  const float* W_post  = (const float*)d_in[10];
  const float* W_hg    = (const float*)d_in[11];
  const float* b_hg    = (const float*)d_in[12];
  const float* W_vg    = (const float*)d_in[13];
  const float* b_vg    = (const float*)d_in[14];
  const float* Wo      = (const float*)d_in[15];
  float* out = (float*)d_out;
  float* ws  = (float*)d_ws;

  // workspace layout (floats); total 21,053,440 floats = 80.4 MiB
  float* q_lin = ws;                 // [4096,1024]
  float* k_lin = ws + 4194304;       // [4096,1024]
  float* v_lin = ws + 8388608;       // [4096,1024]
  float* hgbuf = ws + 12582912;      // [4096,16]
  float* vgbuf = ws + 12648448;      // [4096,1024]
  float* mkbuf = ws + 16842752;      // [16,16,64]
  float* aobuf = ws + 16859136;      // [4096,1024]

  dim3 blk(256);
  gemm_f32<<<dim3(16, 64), blk, 0, stream>>>(x, Wq, q_lin, 4096, 1024, 1024);
  gemm_f32<<<dim3(16, 64), blk, 0, stream>>>(x, Wk, k_lin, 4096, 1024, 1024);
  gemm_f32<<<dim3(16, 64), blk, 0, stream>>>(x, Wv, v_lin, 4096, 1024, 1024);
  gemm_f32<<<dim3(16, 64), blk, 0, stream>>>(x, W_vg, vgbuf, 4096, 1024, 1024);
  gemm_f32<<<dim3(1, 64),  blk, 0, stream>>>(x, W_hg, hgbuf, 4096, 16, 1024);
  qk_post<<<16384, blk, 0, stream>>>(q_lin, q_scale, freqs);
  qk_post<<<16384, blk, 0, stream>>>(k_lin, k_scale, freqs);
  memk_post<<<64, blk, 0, stream>>>(mem_k, k_scale, mkbuf);
  sigmoid_bias<<<256, blk, 0, stream>>>(hgbuf, b_hg, 65536, 15);
  sigmoid_bias<<<16384, blk, 0, stream>>>(vgbuf, b_vg, 4194304, 1023);
  attn_fused<<<4096, blk, 0, stream>>>(q_lin, k_lin, v_lin, mkbuf, mem_v,
                                       W_pre, W_post, hgbuf, vgbuf, aobuf);
  gemm_f32<<<dim3(16, 64), blk, 0, stream>>>(aobuf, Wo, out, 4096, 1024, 1024);
}

// Round 2
// 2162.220 us; speedup vs baseline: 1.2518x; 1.2518x over previous
//
#include <hip/hip_runtime.h>
#include <hip/hip_bf16.h>
#include <cmath>

// B=4, N=1024, DIM=1024, H=16, DH=64, M=16, QK_SCALE=10
#define M_ 16

__device__ __forceinline__ float bf_hi(unsigned u) {
  unsigned x = u & 0xFFFF0000u; return __builtin_bit_cast(float, x);
}
__device__ __forceinline__ float bf_lo(unsigned u) {
  unsigned x = u << 16; return __builtin_bit_cast(float, x);
}
__device__ __forceinline__ unsigned short to_bf(float f) {
  __hip_bfloat16 h = __float2bfloat16(f);
  return __builtin_bit_cast(unsigned short, h);
}

// ---------------- GEMM: C[M x N] = A[M x K] @ B[K x N], fp32, 64x64 tile ----
__global__ __launch_bounds__(256)
void gemm_f32(const float* __restrict__ A, const float* __restrict__ Bm,
              float* __restrict__ C, int Mm, int N, int K)
{
  __shared__ float As[16][68];
  __shared__ float Bs[16][68];
  const int t = threadIdx.x;
  const int tx = t & 15, ty = t >> 4;
  const int row0 = blockIdx.y * 64, col0 = blockIdx.x * 64;
  float acc[4][4];
#pragma unroll
  for (int i = 0; i < 4; ++i)
#pragma unroll
    for (int j = 0; j < 4; ++j) acc[i][j] = 0.f;

  for (int kk = 0; kk < K; kk += 16) {
#pragma unroll
    for (int q = 0; q < 4; ++q) {
      int idx = t + q * 256;
      int c = idx & 15, r = idx >> 4;
      As[c][r] = A[(size_t)(row0 + r) * K + kk + c];
    }
#pragma unroll
    for (int q = 0; q < 4; ++q) {
      int idx = t + q * 256;
      int cb = idx & 63, rb = idx >> 6;
      int col = col0 + cb;
      Bs[rb][cb] = (col < N) ? Bm[(size_t)(kk + rb) * N + col] : 0.f;
    }
    __syncthreads();
#pragma unroll
    for (int k2 = 0; k2 < 16; ++k2) {
      float4 a4 = *(const float4*)&As[k2][ty << 2];
      float4 b4 = *(const float4*)&Bs[k2][tx << 2];
      float a[4] = {a4.x, a4.y, a4.z, a4.w};
      float b[4] = {b4.x, b4.y, b4.z, b4.w};
#pragma unroll
      for (int i = 0; i < 4; ++i)
#pragma unroll
        for (int j = 0; j < 4; ++j) acc[i][j] += a[i] * b[j];
    }
    __syncthreads();
  }
#pragma unroll
  for (int i = 0; i < 4; ++i) {
    int row = row0 + (ty << 2) + i;
#pragma unroll
    for (int j = 0; j < 4; ++j) {
      int col = col0 + (tx << 2) + j;
      if (col < N) C[(size_t)row * N + col] = acc[i][j];
    }
  }
}

// --------- GEMM writing bf16 into vall interior ([b][16+n][1024]) ----------
__global__ __launch_bounds__(256)
void gemm_bf16out(const float* __restrict__ A, const float* __restrict__ Bm,
                  unsigned short* __restrict__ vall, int K)
{
  __shared__ float As[16][68];
  __shared__ float Bs[16][68];
  const int t = threadIdx.x;
  const int tx = t & 15, ty = t >> 4;
  const int row0 = blockIdx.y * 64, col0 = blockIdx.x * 64;
  float acc[4][4];
#pragma unroll
  for (int i = 0; i < 4; ++i)
#pragma unroll
    for (int j = 0; j < 4; ++j) acc[i][j] = 0.f;

  for (int kk = 0; kk < K; kk += 16) {
#pragma unroll
    for (int q = 0; q < 4; ++q) {
      int idx = t + q * 256;
      int c = idx & 15, r = idx >> 4;
      As[c][r] = A[(size_t)(row0 + r) * K + kk + c];
    }
#pragma unroll
    for (int q = 0; q < 4; ++q) {
      int idx = t + q * 256;
      int cb = idx & 63, rb = idx >> 6;
      Bs[rb][cb] = Bm[(size_t)(kk + rb) * 1024 + col0 + cb];
    }
    __syncthreads();
#pragma unroll
    for (int k2 = 0; k2 < 16; ++k2) {
      float4 a4 = *(const float4*)&As[k2][ty << 2];
      float4 b4 = *(const float4*)&Bs[k2][tx << 2];
      float a[4] = {a4.x, a4.y, a4.z, a4.w};
      float b[4] = {b4.x, b4.y, b4.z, b4.w};
#pragma unroll
      for (int i = 0; i < 4; ++i)
#pragma unroll
        for (int j = 0; j < 4; ++j) acc[i][j] += a[i] * b[j];
    }
    __syncthreads();
  }
#pragma unroll
  for (int i = 0; i < 4; ++i) {
    int row = row0 + (ty << 2) + i;           // b*1024 + n
    int b = row >> 10, n = row & 1023;
    size_t orow = (size_t)(b * 1040 + 16 + n);
#pragma unroll
    for (int j = 0; j < 4; ++j) {
      int col = col0 + (tx << 2) + j;
      vall[orow * 1024 + col] = to_bf(acc[i][j]);
    }
  }
}

// ------------- q postprocess: in-place l2norm * scale, then rope ------------
__global__ __launch_bounds__(256)
void qk_post(float* __restrict__ qk, const float* __restrict__ scale,
             const float* __restrict__ freqs)
{
  int gid = blockIdx.x * 256 + threadIdx.x;
  int d = gid & 63;
  int row = gid >> 6;            // (b*N+n)*H + h
  int h = row & 15;
  int n = (row >> 4) & 1023;
  float v = qk[gid];
  float ss = v * v;
#pragma unroll
  for (int off = 32; off; off >>= 1) ss += __shfl_xor(ss, off);
  v = v / fmaxf(sqrtf(ss), 1e-12f) * scale[(h << 6) + d];
  float f = freqs[(n << 6) + d];
  float other = __shfl_xor(v, 1);
  float rot = (d & 1) ? other : -other;
  qk[gid] = v * cosf(f) + rot * sinf(f);
}

// -------- k postprocess: l2norm*scale + rope, write bf16 into kall ----------
__global__ __launch_bounds__(256)
void k_post_bf(const float* __restrict__ k_lin, const float* __restrict__ scale,
               const float* __restrict__ freqs, unsigned short* __restrict__ kall)
{
  int gid = blockIdx.x * 256 + threadIdx.x;
  int d = gid & 63;
  int row = gid >> 6;            // (b*N+n)*H + h
  int h = row & 15;
  int n = (row >> 4) & 1023;
  int b = row >> 14;
  float v = k_lin[gid];
  float ss = v * v;
#pragma unroll
  for (int off = 32; off; off >>= 1) ss += __shfl_xor(ss, off);
  v = v / fmaxf(sqrtf(ss), 1e-12f) * scale[(h << 6) + d];
  float f = freqs[(n << 6) + d];
  float other = __shfl_xor(v, 1);
  float rot = (d & 1) ? other : -other;
  float out = v * cosf(f) + rot * sinf(f);
  kall[(size_t)(b * 1040 + 16 + n) * 1024 + (h << 6) + d] = to_bf(out);
}

// -------- memory slots: k = l2norm(mem_k)*k_scale, v = mem_v (bf16) ---------
__global__ __launch_bounds__(256)
void mem_build(const float* __restrict__ mem_k, const float* __restrict__ mem_v,
               const float* __restrict__ k_scale,
               unsigned short* __restrict__ kall, unsigned short* __restrict__ vall)
{
  int gid = blockIdx.x * 256 + threadIdx.x;   // 16384 = H*M*64
  int d = gid & 63;
  int row = gid >> 6;            // h*M + m
  int h = row >> 4, m = row & 15;
  float v = mem_k[gid];
  float ss = v * v;
#pragma unroll
  for (int off = 32; off; off >>= 1) ss += __shfl_xor(ss, off);
  unsigned short kb = to_bf(v / fmaxf(sqrtf(ss), 1e-12f) * k_scale[(h << 6) + d]);
  unsigned short vb = to_bf(mem_v[gid]);
#pragma unroll
  for (int b = 0; b < 4; ++b) {
    size_t o = (size_t)(b * 1040 + m) * 1024 + (h << 6) + d;
    kall[o] = kb;
    vall[o] = vb;
  }
}

// ------------- sigmoid(x + bias[idx & mask]) in place -----------------------
__global__ __launch_bounds__(256)
void sigmoid_bias(float* __restrict__ x, const float* __restrict__ bias,
                  int n, int mask)
{
  int idx = blockIdx.x * 256 + threadIdx.x;
  if (idx < n) {
    float v = x[idx] + bias[idx & mask];
    x[idx] = 1.f / (1.f + __expf(-v));
  }
}

// ------------- fused attention with talking heads, 8-query tiles ------------
// Block = (b, 8 queries). 4 waves; wave w owns i_local {w, w+4}.
// Lane = (h = lane>>2, part = lane&3): 16-float fragment of the 64-dim head.
// No running max: |mixed logit| <= ~29, exp(m - 20) is fp32-safe.
__global__ __launch_bounds__(256)
void attn_fused(const float* __restrict__ q_lin, const unsigned short* __restrict__ kall,
                const unsigned short* __restrict__ vall, const float* __restrict__ W_pre,
                const float* __restrict__ W_post, const float* __restrict__ hgate,
                const float* __restrict__ vgate, float* __restrict__ attn_out)
{
  __shared__ float sS[16 * 513];          // [g][c], c = i_local*64 + jj, +1 pad
  __shared__ float sWpre[256], sWpost[256];
  __shared__ float sIL[128];              // [g][i_local]

  const int t = threadIdx.x;
  const int lane = t & 63, w = t >> 6;
  const int raw = blockIdx.x;
  const int b = raw & 3, tile = raw >> 2; // batch tied to XCD (raw%8) for L2 locality
  const int i0 = tile << 3;
  const int jmax = i0 + 24;               // last visible kv row = i0+7+16

  sWpre[t] = W_pre[t];
  sWpost[t] = W_post[t];

  // q fragments, QK_SCALE folded
  float4 qv[2][4];
#pragma unroll
  for (int ii = 0; ii < 2; ++ii) {
    int irow = (b << 10) + i0 + w + (ii << 2);
    const float4* qr = (const float4*)(q_lin + ((size_t)irow << 10));
#pragma unroll
    for (int u = 0; u < 4; ++u) {
      float4 qq = qr[(lane << 2) + u];
      qq.x *= 10.f; qq.y *= 10.f; qq.z *= 10.f; qq.w *= 10.f;
      qv[ii][u] = qq;
    }
  }

  float partL[2][16];
#pragma unroll
  for (int s = 0; s < 2; ++s)
#pragma unroll
    for (int g = 0; g < 16; ++g) partL[s][g] = 0.f;

  // =========================== PASS 1: denominators ==========================
  for (int base = 0; base < jmax; base += 64) {
    const int tc = min(64, jmax - base);
    __syncthreads();
    // ---- dots: wave computes S[h][i][jj] for its 2 i's, all jj ----
#pragma unroll 2
    for (int jj = 0; jj < tc; ++jj) {
      const int j = base + jj;
      const uint4* kp = (const uint4*)(kall + (((size_t)(b * 1040 + j)) << 10) + (lane << 4));
      uint4 k0 = kp[0], k1 = kp[1];
      float kf[16];
      kf[0] = bf_lo(k0.x); kf[1] = bf_hi(k0.x); kf[2] = bf_lo(k0.y); kf[3] = bf_hi(k0.y);
      kf[4] = bf_lo(k0.z); kf[5] = bf_hi(k0.z); kf[6] = bf_lo(k0.w); kf[7] = bf_hi(k0.w);
      kf[8] = bf_lo(k1.x); kf[9] = bf_hi(k1.x); kf[10] = bf_lo(k1.y); kf[11] = bf_hi(k1.y);
      kf[12] = bf_lo(k1.z); kf[13] = bf_hi(k1.z); kf[14] = bf_lo(k1.w); kf[15] = bf_hi(k1.w);
#pragma unroll
      for (int ii = 0; ii < 2; ++ii) {
        float acc = qv[ii][0].x * kf[0] + qv[ii][0].y * kf[1] + qv[ii][0].z * kf[2] + qv[ii][0].w * kf[3]
                  + qv[ii][1].x * kf[4] + qv[ii][1].y * kf[5] + qv[ii][1].z * kf[6] + qv[ii][1].w * kf[7]
                  + qv[ii][2].x * kf[8] + qv[ii][2].y * kf[9] + qv[ii][2].z * kf[10] + qv[ii][2].w * kf[11]
                  + qv[ii][3].x * kf[12] + qv[ii][3].y * kf[13] + qv[ii][3].z * kf[14] + qv[ii][3].w * kf[15];
        acc += __shfl_xor(acc, 1);
        acc += __shfl_xor(acc, 2);
        if ((lane & 3) == 0) sS[(lane >> 2) * 513 + ((w + (ii << 2)) << 6) + jj] = acc;
      }
    }
    __syncthreads();
    // ---- mix W_pre + exp, accumulate denominators in registers ----
#pragma unroll
    for (int slot = 0; slot < 2; ++slot) {
      const int c = t + (slot << 8);
      const int il = c >> 6, jj = c & 63;
      const int j = base + jj;
      if (jj < tc && j <= i0 + il + 16) {
        float ch[16];
#pragma unroll
        for (int g = 0; g < 16; ++g) ch[g] = sS[g * 513 + c];
#pragma unroll
        for (int g2 = 0; g2 < 16; ++g2) {
          const float4* wr = (const float4*)&sWpre[g2 << 4];
          float4 w0 = wr[0], w1 = wr[1], w2 = wr[2], w3 = wr[3];
          float mm = w0.x * ch[0] + w0.y * ch[1] + w0.z * ch[2] + w0.w * ch[3]
                   + w1.x * ch[4] + w1.y * ch[5] + w1.z * ch[6] + w1.w * ch[7]
                   + w2.x * ch[8] + w2.y * ch[9] + w2.z * ch[10] + w2.w * ch[11]
                   + w3.x * ch[12] + w3.y * ch[13] + w3.z * ch[14] + w3.w * ch[15];
          partL[slot][g2] += __expf(mm - 20.f);
        }
      }
    }
  }
  // wave-reduce denominators (wave w holds i = w (slot 0) and w+4 (slot 1))
#pragma unroll
  for (int slot = 0; slot < 2; ++slot)
#pragma unroll
    for (int g = 0; g < 16; ++g) {
      float s = partL[slot][g];
#pragma unroll
      for (int off = 32; off; off >>= 1) s += __shfl_xor(s, off);
      if (lane == 0) sIL[(g << 3) + w + (slot << 2)] = 1.f / s;
    }

  // =========================== PASS 2: probs + PV ============================
  float4 vacc[2][4];
#pragma unroll
  for (int ii = 0; ii < 2; ++ii)
#pragma unroll
    for (int u = 0; u < 4; ++u) vacc[ii][u] = make_float4(0.f, 0.f, 0.f, 0.f);

  for (int base = 0; base < jmax; base += 64) {
    const int tc = min(64, jmax - base);
    __syncthreads();
#pragma unroll 2
    for (int jj = 0; jj < tc; ++jj) {
      const int j = base + jj;
      const uint4* kp = (const uint4*)(kall + (((size_t)(b * 1040 + j)) << 10) + (lane << 4));
      uint4 k0 = kp[0], k1 = kp[1];
      float kf[16];
      kf[0] = bf_lo(k0.x); kf[1] = bf_hi(k0.x); kf[2] = bf_lo(k0.y); kf[3] = bf_hi(k0.y);
      kf[4] = bf_lo(k0.z); kf[5] = bf_hi(k0.z); kf[6] = bf_lo(k0.w); kf[7] = bf_hi(k0.w);
      kf[8] = bf_lo(k1.x); kf[9] = bf_hi(k1.x); kf[10] = bf_lo(k1.y); kf[11] = bf_hi(k1.y);
      kf[12] = bf_lo(k1.z); kf[13] = bf_hi(k1.z); kf[14] = bf_lo(k1.w); kf[15] = bf_hi(k1.w);
#pragma unroll
      for (int ii = 0; ii < 2; ++ii) {
        float acc = qv[ii][0].x * kf[0] + qv[ii][0].y * kf[1] + qv[ii][0].z * kf[2] + qv[ii][0].w * kf[3]
                  + qv[ii][1].x * kf[4] + qv[ii][1].y * kf[5] + qv[ii][1].z * kf[6] + qv[ii][1].w * kf[7]
                  + qv[ii][2].x * kf[8] + qv[ii][2].y * kf[9] + qv[ii][2].z * kf[10] + qv[ii][2].w * kf[11]
                  + qv[ii][3].x * kf[12] + qv[ii][3].y * kf[13] + qv[ii][3].z * kf[14] + qv[ii][3].w * kf[15];
        acc += __shfl_xor(acc, 1);
        acc += __shfl_xor(acc, 2);
        if ((lane & 3) == 0) sS[(lane >> 2) * 513 + ((w + (ii << 2)) << 6) + jj] = acc;
      }
    }
    __syncthreads();
    // ---- probs: e/l then W_post mix; write p2 back into sS (same column) ----
#pragma unroll
    for (int slot = 0; slot < 2; ++slot) {
      const int c = t + (slot << 8);
      const int il = c >> 6, jj = c & 63;
      const int j = base + jj;
      if (jj < tc) {
        const bool ok = (j <= i0 + il + 16);
        float e[16];
        if (ok) {
          float ch[16];
#pragma unroll
          for (int g = 0; g < 16; ++g) ch[g] = sS[g * 513 + c];
#pragma unroll
          for (int g2 = 0; g2 < 16; ++g2) {
            const float4* wr = (const float4*)&sWpre[g2 << 4];
            float4 w0 = wr[0], w1 = wr[1], w2 = wr[2], w3 = wr[3];
            float mm = w0.x * ch[0] + w0.y * ch[1] + w0.z * ch[2] + w0.w * ch[3]
                     + w1.x * ch[4] + w1.y * ch[5] + w1.z * ch[6] + w1.w * ch[7]
                     + w2.x * ch[8] + w2.y * ch[9] + w2.z * ch[10] + w2.w * ch[11]
                     + w3.x * ch[12] + w3.y * ch[13] + w3.z * ch[14] + w3.w * ch[15];
            e[g2] = __expf(mm - 20.f) * sIL[(g2 << 3) + il];
          }
        } else {
#pragma unroll
          for (int g = 0; g < 16; ++g) e[g] = 0.f;
        }
#pragma unroll
        for (int g2 = 0; g2 < 16; ++g2) {
          const float4* wr = (const float4*)&sWpost[g2 << 4];
          float4 w0 = wr[0], w1 = wr[1], w2 = wr[2], w3 = wr[3];
          float p = w0.x * e[0] + w0.y * e[1] + w0.z * e[2] + w0.w * e[3]
                  + w1.x * e[4] + w1.y * e[5] + w1.z * e[6] + w1.w * e[7]
                  + w2.x * e[8] + w2.y * e[9] + w2.z * e[10] + w2.w * e[11]
                  + w3.x * e[12] + w3.y * e[13] + w3.z * e[14] + w3.w * e[15];
          sS[g2 * 513 + c] = p;
        }
      }
    }
    __syncthreads();
    // ---- PV: lane = (g' = lane>>2, part), accumulate wave's 2 i's ----
#pragma unroll 4
    for (int jj = 0; jj < tc; ++jj) {
      const int j = base + jj;
      const uint4* vp = (const uint4*)(vall + (((size_t)(b * 1040 + j)) << 10) + (lane << 4));
      uint4 v0 = vp[0], v1 = vp[1];
      float vf[16];
      vf[0] = bf_lo(v0.x); vf[1] = bf_hi(v0.x); vf[2] = bf_lo(v0.y); vf[3] = bf_hi(v0.y);
      vf[4] = bf_lo(v0.z); vf[5] = bf_hi(v0.z); vf[6] = bf_lo(v0.w); vf[7] = bf_hi(v0.w);
      vf[8] = bf_lo(v1.x); vf[9] = bf_hi(v1.x); vf[10] = bf_lo(v1.y); vf[11] = bf_hi(v1.y);
      vf[12] = bf_lo(v1.z); vf[13] = bf_hi(v1.z); vf[14] = bf_lo(v1.w); vf[15] = bf_hi(v1.w);
#pragma unroll
      for (int ii = 0; ii < 2; ++ii) {
        float p = sS[(lane >> 2) * 513 + ((w + (ii << 2)) << 6) + jj];
#pragma unroll
        for (int u = 0; u < 4; ++u) {
          vacc[ii][u].x += p * vf[u * 4 + 0];
          vacc[ii][u].y += p * vf[u * 4 + 1];
          vacc[ii][u].z += p * vf[u * 4 + 2];
          vacc[ii][u].w += p * vf[u * 4 + 3];
        }
      }
    }
  }

  // epilogue: head gate + per-dim value gate, store fp32
#pragma unroll
  for (int ii = 0; ii < 2; ++ii) {
    const int irow = (b << 10) + i0 + w + (ii << 2);
    const float hg = hgate[irow * 16 + (lane >> 2)];
    const float4* vg = (const float4*)(vgate + ((size_t)irow << 10) + (lane << 4));
    float4* op = (float4*)(attn_out + ((size_t)irow << 10) + (lane << 4));
#pragma unroll
    for (int u = 0; u < 4; ++u) {
      float4 g = vg[u];
      float4 o;
      o.x = vacc[ii][u].x * hg * g.x;
      o.y = vacc[ii][u].y * hg * g.y;
      o.z = vacc[ii][u].z * hg * g.z;
      o.w = vacc[ii][u].w * hg * g.w;
      op[u] = o;
    }
  }
}

extern "C" void kernel_launch(void* const* d_in, const int* in_sizes, int n_in,
                              void* d_out, int out_size, void* d_ws, size_t ws_size,
                              hipStream_t stream)
{
  const float* x       = (const float*)d_in[0];
  const float* freqs   = (const float*)d_in[1];
  const float* Wq      = (const float*)d_in[2];
  const float* Wk      = (const float*)d_in[3];
  const float* Wv      = (const float*)d_in[4];
  const float* q_scale = (const float*)d_in[5];
  const float* k_scale = (const float*)d_in[6];
  const float* mem_k   = (const float*)d_in[7];
  const float* mem_v   = (const float*)d_in[8];
  const float* W_pre   = (const float*)d_in[9];
  const float* W_post  = (const float*)d_in[10];
  const float* W_hg    = (const float*)d_in[11];
  const float* b_hg    = (const float*)d_in[12];
  const float* W_vg    = (const float*)d_in[13];
  const float* b_vg    = (const float*)d_in[14];
  const float* Wo      = (const float*)d_in[15];
  float* out = (float*)d_out;
  float* ws  = (float*)d_ws;

  // workspace (floats). aobuf aliases k_lin (k_lin dead after k_post_bf).
  float* q_lin = ws;                               // [4096,1024]
  float* k_lin = ws + 4194304;                     // [4096,1024] (later aobuf)
  float* aobuf = k_lin;
  float* hgbuf = ws + 8388608;                     // [4096,16]
  float* vgbuf = ws + 8454144;                     // [4096,1024]
  unsigned short* kall = (unsigned short*)(ws + 12648448);  // [4,1040,1024] bf16
  unsigned short* vall = (unsigned short*)(ws + 14778368);  // [4,1040,1024] bf16
  // end: 16,908,288 floats = 67.6 MiB

  dim3 blk(256);
  gemm_f32<<<dim3(16, 64), blk, 0, stream>>>(x, Wq, q_lin, 4096, 1024, 1024);
  gemm_f32<<<dim3(16, 64), blk, 0, stream>>>(x, Wk, k_lin, 4096, 1024, 1024);
  gemm_bf16out<<<dim3(16, 64), blk, 0, stream>>>(x, Wv, vall, 1024);
  gemm_f32<<<dim3(16, 64), blk, 0, stream>>>(x, W_vg, vgbuf, 4096, 1024, 1024);
  gemm_f32<<<dim3(1, 64),  blk, 0, stream>>>(x, W_hg, hgbuf, 4096, 16, 1024);
  qk_post<<<16384, blk, 0, stream>>>(q_lin, q_scale, freqs);
  k_post_bf<<<16384, blk, 0, stream>>>(k_lin, k_scale, freqs, kall);
  mem_build<<<64, blk, 0, stream>>>(mem_k, mem_v, k_scale, kall, vall);
  sigmoid_bias<<<256, blk, 0, stream>>>(hgbuf, b_hg, 65536, 15);
  sigmoid_bias<<<16384, blk, 0, stream>>>(vgbuf, b_vg, 4194304, 1023);
  attn_fused<<<512, blk, 0, stream>>>(q_lin, kall, vall, W_pre, W_post,
                                      hgbuf, vgbuf, aobuf);
  gemm_f32<<<dim3(16, 64), blk, 0, stream>>>(aobuf, Wo, out, 4096, 1024, 1024);
}

// Round 3
// 1590.221 us; speedup vs baseline: 1.7021x; 1.3597x over previous
//
#include <hip/hip_runtime.h>
#include <hip/hip_bf16.h>
#include <cmath>

// B=4, N=1024, DIM=1024, H=16, DH=64, M=16, QK_SCALE=10
#define M_ 16

typedef __attribute__((ext_vector_type(8))) short short8;
typedef __attribute__((ext_vector_type(4))) float f32x4;

__device__ __forceinline__ float bf_hi(unsigned u) {
  unsigned x = u & 0xFFFF0000u; return __builtin_bit_cast(float, x);
}
__device__ __forceinline__ float bf_lo(unsigned u) {
  unsigned x = u << 16; return __builtin_bit_cast(float, x);
}
__device__ __forceinline__ unsigned short to_bf(float f) {
  __hip_bfloat16 h = __float2bfloat16(f);
  return __builtin_bit_cast(unsigned short, h);
}

// ---------------- fp32 GEMM (kept only for the tiny hgate proj) -------------
__global__ __launch_bounds__(256)
void gemm_f32(const float* __restrict__ A, const float* __restrict__ Bm,
              float* __restrict__ C, int Mm, int N, int K)
{
  __shared__ float As[16][68];
  __shared__ float Bs[16][68];
  const int t = threadIdx.x;
  const int tx = t & 15, ty = t >> 4;
  const int row0 = blockIdx.y * 64, col0 = blockIdx.x * 64;
  float acc[4][4];
#pragma unroll
  for (int i = 0; i < 4; ++i)
#pragma unroll
    for (int j = 0; j < 4; ++j) acc[i][j] = 0.f;

  for (int kk = 0; kk < K; kk += 16) {
#pragma unroll
    for (int q = 0; q < 4; ++q) {
      int idx = t + q * 256;
      int c = idx & 15, r = idx >> 4;
      As[c][r] = A[(size_t)(row0 + r) * K + kk + c];
    }
#pragma unroll
    for (int q = 0; q < 4; ++q) {
      int idx = t + q * 256;
      int cb = idx & 63, rb = idx >> 6;
      int col = col0 + cb;
      Bs[rb][cb] = (col < N) ? Bm[(size_t)(kk + rb) * N + col] : 0.f;
    }
    __syncthreads();
#pragma unroll
    for (int k2 = 0; k2 < 16; ++k2) {
      float4 a4 = *(const float4*)&As[k2][ty << 2];
      float4 b4 = *(const float4*)&Bs[k2][tx << 2];
      float a[4] = {a4.x, a4.y, a4.z, a4.w};
      float b[4] = {b4.x, b4.y, b4.z, b4.w};
#pragma unroll
      for (int i = 0; i < 4; ++i)
#pragma unroll
        for (int j = 0; j < 4; ++j) acc[i][j] += a[i] * b[j];
    }
    __syncthreads();
  }
#pragma unroll
  for (int i = 0; i < 4; ++i) {
    int row = row0 + (ty << 2) + i;
#pragma unroll
    for (int j = 0; j < 4; ++j) {
      int col = col0 + (tx << 2) + j;
      if (col < N) C[(size_t)row * N + col] = acc[i][j];
    }
  }
}

// -------- fp32 -> bf16 elementwise (x, and attention-out before Wo) ---------
__global__ __launch_bounds__(256)
void cvt_bf16x4(const float* __restrict__ in, unsigned short* __restrict__ out, int n4)
{
  int i = blockIdx.x * 256 + threadIdx.x;
  if (i < n4) {
    float4 v = ((const float4*)in)[i];
    ushort4 o;
    o.x = to_bf(v.x); o.y = to_bf(v.y); o.z = to_bf(v.z); o.w = to_bf(v.w);
    ((ushort4*)out)[i] = o;
  }
}

// -------- W [1024 k][1024 n] fp32 -> WT [n][k] bf16 (64x64 LDS tiles) -------
__global__ __launch_bounds__(256)
void transpose_to_bf(const float* __restrict__ W, unsigned short* __restrict__ WT)
{
  __shared__ float tile[64][65];
  const int n0 = blockIdx.x * 64, k0 = blockIdx.y * 64;
  const int t = threadIdx.x, c = t & 63, r4 = t >> 6;
#pragma unroll
  for (int q = 0; q < 16; ++q) {
    int r = (q << 2) + r4;
    tile[r][c] = W[(size_t)(k0 + r) * 1024 + n0 + c];
  }
  __syncthreads();
#pragma unroll
  for (int q = 0; q < 16; ++q) {
    int r = (q << 2) + r4;
    WT[(size_t)(n0 + r) * 1024 + k0 + c] = to_bf(tile[c][r]);
  }
}

// -------- bf16 MFMA GEMM: C[4096][1024] = A[4096][1024] @ WT[1024][1024]^T --
// tile 128x64, BK=32, 4 waves in 2x2; mode 0: fp32 C; mode 1: bf16 into vall.
__global__ __launch_bounds__(256)
void gemm_bf(const unsigned short* __restrict__ A, const unsigned short* __restrict__ BT,
             float* __restrict__ C, unsigned short* __restrict__ Vout, int mode)
{
  __shared__ __align__(16) unsigned short Abuf[128 * 32];
  __shared__ __align__(16) unsigned short Bbuf[64 * 32];
  const int t = threadIdx.x, lane = t & 63, w = t >> 6;
  const int wm = w & 1, wn = w >> 1;
  const int col0 = blockIdx.x * 64, row0 = blockIdx.y * 128;

  f32x4 acc[4][2];
#pragma unroll
  for (int mi = 0; mi < 4; ++mi)
#pragma unroll
    for (int ni = 0; ni < 2; ++ni) acc[mi][ni] = (f32x4){0.f, 0.f, 0.f, 0.f};

  for (int kk = 0; kk < 1024; kk += 32) {
    // stage A-tile (128x32) and B-tile (64x32), 16B chunks, chunk c -> LDS byte c*16
#pragma unroll
    for (int q = 0; q < 2; ++q) {
      int c = (q << 8) + t;
      int r = c >> 2, kp = c & 3;
      uint4 val = *(const uint4*)(A + (size_t)(row0 + r) * 1024 + kk + kp * 8);
      *(uint4*)((char*)Abuf + c * 16) = val;
    }
    {
      int c = t;
      int r = c >> 2, kp = c & 3;
      uint4 val = *(const uint4*)(BT + (size_t)(col0 + r) * 1024 + kk + kp * 8);
      *(uint4*)((char*)Bbuf + c * 16) = val;
    }
    __syncthreads();
    short8 af[4], bfr[2];
#pragma unroll
    for (int mi = 0; mi < 4; ++mi)
      af[mi] = *(const short8*)((char*)Abuf + ((wm << 6) + (mi << 4) + (lane & 15)) * 64 + (lane >> 4) * 16);
#pragma unroll
    for (int ni = 0; ni < 2; ++ni)
      bfr[ni] = *(const short8*)((char*)Bbuf + ((wn << 5) + (ni << 4) + (lane & 15)) * 64 + (lane >> 4) * 16);
#pragma unroll
    for (int mi = 0; mi < 4; ++mi)
#pragma unroll
      for (int ni = 0; ni < 2; ++ni)
        acc[mi][ni] = __builtin_amdgcn_mfma_f32_16x16x32_bf16(af[mi], bfr[ni], acc[mi][ni], 0, 0, 0);
    __syncthreads();
  }

  // C/D layout: col = lane&15, row = (lane>>4)*4 + reg
#pragma unroll
  for (int mi = 0; mi < 4; ++mi)
#pragma unroll
    for (int ni = 0; ni < 2; ++ni)
#pragma unroll
      for (int reg = 0; reg < 4; ++reg) {
        int m = row0 + (wm << 6) + (mi << 4) + ((lane >> 4) << 2) + reg;
        int n = col0 + (wn << 5) + (ni << 4) + (lane & 15);
        float v = acc[mi][ni][reg];
        if (mode == 0) {
          C[((size_t)m << 10) + n] = v;
        } else {
          int b = m >> 10, nn = m & 1023;
          Vout[((size_t)(b * 1040 + 16 + nn) << 10) + n] = to_bf(v);
        }
      }
}

// ------------- q postprocess: in-place l2norm * scale, then rope ------------
__global__ __launch_bounds__(256)
void qk_post(float* __restrict__ qk, const float* __restrict__ scale,
             const float* __restrict__ freqs)
{
  int gid = blockIdx.x * 256 + threadIdx.x;
  int d = gid & 63;
  int row = gid >> 6;
  int h = row & 15;
  int n = (row >> 4) & 1023;
  float v = qk[gid];
  float ss = v * v;
#pragma unroll
  for (int off = 32; off; off >>= 1) ss += __shfl_xor(ss, off);
  v = v / fmaxf(sqrtf(ss), 1e-12f) * scale[(h << 6) + d];
  float f = freqs[(n << 6) + d];
  float other = __shfl_xor(v, 1);
  float rot = (d & 1) ? other : -other;
  qk[gid] = v * cosf(f) + rot * sinf(f);
}

// -------- k postprocess: l2norm*scale + rope, write bf16 into kall ----------
__global__ __launch_bounds__(256)
void k_post_bf(const float* __restrict__ k_lin, const float* __restrict__ scale,
               const float* __restrict__ freqs, unsigned short* __restrict__ kall)
{
  int gid = blockIdx.x * 256 + threadIdx.x;
  int d = gid & 63;
  int row = gid >> 6;
  int h = row & 15;
  int n = (row >> 4) & 1023;
  int b = row >> 14;
  float v = k_lin[gid];
  float ss = v * v;
#pragma unroll
  for (int off = 32; off; off >>= 1) ss += __shfl_xor(ss, off);
  v = v / fmaxf(sqrtf(ss), 1e-12f) * scale[(h << 6) + d];
  float f = freqs[(n << 6) + d];
  float other = __shfl_xor(v, 1);
  float rot = (d & 1) ? other : -other;
  float out = v * cosf(f) + rot * sinf(f);
  kall[(size_t)(b * 1040 + 16 + n) * 1024 + (h << 6) + d] = to_bf(out);
}

// -------- memory slots: k = l2norm(mem_k)*k_scale, v = mem_v (bf16) ---------
__global__ __launch_bounds__(256)
void mem_build(const float* __restrict__ mem_k, const float* __restrict__ mem_v,
               const float* __restrict__ k_scale,
               unsigned short* __restrict__ kall, unsigned short* __restrict__ vall)
{
  int gid = blockIdx.x * 256 + threadIdx.x;   // 16384 = H*M*64
  int d = gid & 63;
  int row = gid >> 6;            // h*M + m
  int h = row >> 4, m = row & 15;
  float v = mem_k[gid];
  float ss = v * v;
#pragma unroll
  for (int off = 32; off; off >>= 1) ss += __shfl_xor(ss, off);
  unsigned short kb = to_bf(v / fmaxf(sqrtf(ss), 1e-12f) * k_scale[(h << 6) + d]);
  unsigned short vb = to_bf(mem_v[gid]);
#pragma unroll
  for (int b = 0; b < 4; ++b) {
    size_t o = (size_t)(b * 1040 + m) * 1024 + (h << 6) + d;
    kall[o] = kb;
    vall[o] = vb;
  }
}

// ------------- sigmoid(x + bias[idx & mask]) in place -----------------------
__global__ __launch_bounds__(256)
void sigmoid_bias(float* __restrict__ x, const float* __restrict__ bias,
                  int n, int mask)
{
  int idx = blockIdx.x * 256 + threadIdx.x;
  if (idx < n) {
    float v = x[idx] + bias[idx & mask];
    x[idx] = 1.f / (1.f + __expf(-v));
  }
}

// ======================= fused attention, j-split ===========================
// grid 2048: raw&3 = b (XCD-affine), (raw>>2)&127 = q-tile (8 queries), raw>>9
// = split s of 4. Tiles of 64 j; T = ceil(jmax/64); split covers [T*s/4, T*(s+1)/4).
// Wave w owns i_local {w, w+4}; lane = (h=lane>>2, part=lane&3).
// No running max (|mixed logit| <= ~29): partial denominators are additive.

// ---- kernel A: partial softmax denominators -> atomicAdd Lbuf[b][i][g] ----
__global__ __launch_bounds__(256)
void attn_denom(const float* __restrict__ q_lin, const unsigned short* __restrict__ kall,
                const float* __restrict__ W_pre, float* __restrict__ Lbuf)
{
  __shared__ float sS[16 * 513];
  __shared__ float sWpre[256];

  const int t = threadIdx.x;
  const int lane = t & 63, w = t >> 6;
  const int raw = blockIdx.x;
  const int b = raw & 3, tile = (raw >> 2) & 127, s = raw >> 9;
  const int i0 = tile << 3;
  const int jmax = i0 + 24;
  const int T = (jmax + 63) >> 6;
  const int t0 = (T * s) >> 2, t1 = (T * (s + 1)) >> 2;
  if (t0 == t1) return;

  sWpre[t] = W_pre[t];

  float4 qv[2][4];
#pragma unroll
  for (int ii = 0; ii < 2; ++ii) {
    int irow = (b << 10) + i0 + w + (ii << 2);
    const float4* qr = (const float4*)(q_lin + ((size_t)irow << 10));
#pragma unroll
    for (int u = 0; u < 4; ++u) {
      float4 qq = qr[(lane << 2) + u];
      qq.x *= 10.f; qq.y *= 10.f; qq.z *= 10.f; qq.w *= 10.f;
      qv[ii][u] = qq;
    }
  }

  float partL[2][16];
#pragma unroll
  for (int sl = 0; sl < 2; ++sl)
#pragma unroll
    for (int g = 0; g < 16; ++g) partL[sl][g] = 0.f;

  for (int tt = t0; tt < t1; ++tt) {
    const int base = tt << 6;
    const int tc = min(64, jmax - base);
    __syncthreads();
#pragma unroll 2
    for (int jj = 0; jj < tc; ++jj) {
      const int j = base + jj;
      const uint4* kp = (const uint4*)(kall + (((size_t)(b * 1040 + j)) << 10) + (lane << 4));
      uint4 k0 = kp[0], k1 = kp[1];
      float kf[16];
      kf[0] = bf_lo(k0.x); kf[1] = bf_hi(k0.x); kf[2] = bf_lo(k0.y); kf[3] = bf_hi(k0.y);
      kf[4] = bf_lo(k0.z); kf[5] = bf_hi(k0.z); kf[6] = bf_lo(k0.w); kf[7] = bf_hi(k0.w);
      kf[8] = bf_lo(k1.x); kf[9] = bf_hi(k1.x); kf[10] = bf_lo(k1.y); kf[11] = bf_hi(k1.y);
      kf[12] = bf_lo(k1.z); kf[13] = bf_hi(k1.z); kf[14] = bf_lo(k1.w); kf[15] = bf_hi(k1.w);
#pragma unroll
      for (int ii = 0; ii < 2; ++ii) {
        float acc = qv[ii][0].x * kf[0] + qv[ii][0].y * kf[1] + qv[ii][0].z * kf[2] + qv[ii][0].w * kf[3]
                  + qv[ii][1].x * kf[4] + qv[ii][1].y * kf[5] + qv[ii][1].z * kf[6] + qv[ii][1].w * kf[7]
                  + qv[ii][2].x * kf[8] + qv[ii][2].y * kf[9] + qv[ii][2].z * kf[10] + qv[ii][2].w * kf[11]
                  + qv[ii][3].x * kf[12] + qv[ii][3].y * kf[13] + qv[ii][3].z * kf[14] + qv[ii][3].w * kf[15];
        acc += __shfl_xor(acc, 1);
        acc += __shfl_xor(acc, 2);
        if ((lane & 3) == 0) sS[(lane >> 2) * 513 + ((w + (ii << 2)) << 6) + jj] = acc;
      }
    }
    __syncthreads();
#pragma unroll
    for (int slot = 0; slot < 2; ++slot) {
      const int c = t + (slot << 8);
      const int il = c >> 6, jj = c & 63;
      const int j = base + jj;
      if (jj < tc && j <= i0 + il + 16) {
        float ch[16];
#pragma unroll
        for (int g = 0; g < 16; ++g) ch[g] = sS[g * 513 + c];
#pragma unroll
        for (int g2 = 0; g2 < 16; ++g2) {
          const float4* wr = (const float4*)&sWpre[g2 << 4];
          float4 w0 = wr[0], w1 = wr[1], w2 = wr[2], w3 = wr[3];
          float mm = w0.x * ch[0] + w0.y * ch[1] + w0.z * ch[2] + w0.w * ch[3]
                   + w1.x * ch[4] + w1.y * ch[5] + w1.z * ch[6] + w1.w * ch[7]
                   + w2.x * ch[8] + w2.y * ch[9] + w2.z * ch[10] + w2.w * ch[11]
                   + w3.x * ch[12] + w3.y * ch[13] + w3.z * ch[14] + w3.w * ch[15];
          partL[slot][g2] += __expf(mm - 20.f);
        }
      }
    }
  }
#pragma unroll
  for (int slot = 0; slot < 2; ++slot)
#pragma unroll
    for (int g = 0; g < 16; ++g) {
      float sv = partL[slot][g];
#pragma unroll
      for (int off = 32; off; off >>= 1) sv += __shfl_xor(sv, off);
      if (lane == 0)
        atomicAdd(&Lbuf[(((b << 10) + i0 + w + (slot << 2)) << 4) + g], sv);
    }
}

// ---- kernel C: recompute dots, probs with known 1/L, gated PV atomicAdd ----
__global__ __launch_bounds__(256)
void attn_pv(const float* __restrict__ q_lin, const unsigned short* __restrict__ kall,
             const unsigned short* __restrict__ vall, const float* __restrict__ W_pre,
             const float* __restrict__ W_post, const float* __restrict__ hgate,
             const float* __restrict__ vgate, const float* __restrict__ Lbuf,
             float* __restrict__ aobuf)
{
  __shared__ float sS[16 * 513];
  __shared__ float sWpre[256], sWpost[256];
  __shared__ float sIL[128];   // [il][g]

  const int t = threadIdx.x;
  const int lane = t & 63, w = t >> 6;
  const int raw = blockIdx.x;
  const int b = raw & 3, tile = (raw >> 2) & 127, s = raw >> 9;
  const int i0 = tile << 3;
  const int jmax = i0 + 24;
  const int T = (jmax + 63) >> 6;
  const int t0 = (T * s) >> 2, t1 = (T * (s + 1)) >> 2;
  if (t0 == t1) return;

  sWpre[t] = W_pre[t];
  sWpost[t] = W_post[t];
  if (t < 128) sIL[t] = 1.f / Lbuf[(((b << 10) + i0) << 4) + t];

  float4 qv[2][4];
#pragma unroll
  for (int ii = 0; ii < 2; ++ii) {
    int irow = (b << 10) + i0 + w + (ii << 2);
    const float4* qr = (const float4*)(q_lin + ((size_t)irow << 10));
#pragma unroll
    for (int u = 0; u < 4; ++u) {
      float4 qq = qr[(lane << 2) + u];
      qq.x *= 10.f; qq.y *= 10.f; qq.z *= 10.f; qq.w *= 10.f;
      qv[ii][u] = qq;
    }
  }

  float4 vacc[2][4];
#pragma unroll
  for (int ii = 0; ii < 2; ++ii)
#pragma unroll
    for (int u = 0; u < 4; ++u) vacc[ii][u] = make_float4(0.f, 0.f, 0.f, 0.f);

  for (int tt = t0; tt < t1; ++tt) {
    const int base = tt << 6;
    const int tc = min(64, jmax - base);
    __syncthreads();
#pragma unroll 2
    for (int jj = 0; jj < tc; ++jj) {
      const int j = base + jj;
      const uint4* kp = (const uint4*)(kall + (((size_t)(b * 1040 + j)) << 10) + (lane << 4));
      uint4 k0 = kp[0], k1 = kp[1];
      float kf[16];
      kf[0] = bf_lo(k0.x); kf[1] = bf_hi(k0.x); kf[2] = bf_lo(k0.y); kf[3] = bf_hi(k0.y);
      kf[4] = bf_lo(k0.z); kf[5] = bf_hi(k0.z); kf[6] = bf_lo(k0.w); kf[7] = bf_hi(k0.w);
      kf[8] = bf_lo(k1.x); kf[9] = bf_hi(k1.x); kf[10] = bf_lo(k1.y); kf[11] = bf_hi(k1.y);
      kf[12] = bf_lo(k1.z); kf[13] = bf_hi(k1.z); kf[14] = bf_lo(k1.w); kf[15] = bf_hi(k1.w);
#pragma unroll
      for (int ii = 0; ii < 2; ++ii) {
        float acc = qv[ii][0].x * kf[0] + qv[ii][0].y * kf[1] + qv[ii][0].z * kf[2] + qv[ii][0].w * kf[3]
                  + qv[ii][1].x * kf[4] + qv[ii][1].y * kf[5] + qv[ii][1].z * kf[6] + qv[ii][1].w * kf[7]
                  + qv[ii][2].x * kf[8] + qv[ii][2].y * kf[9] + qv[ii][2].z * kf[10] + qv[ii][2].w * kf[11]
                  + qv[ii][3].x * kf[12] + qv[ii][3].y * kf[13] + qv[ii][3].z * kf[14] + qv[ii][3].w * kf[15];
        acc += __shfl_xor(acc, 1);
        acc += __shfl_xor(acc, 2);
        if ((lane & 3) == 0) sS[(lane >> 2) * 513 + ((w + (ii << 2)) << 6) + jj] = acc;
      }
    }
    __syncthreads();
#pragma unroll
    for (int slot = 0; slot < 2; ++slot) {
      const int c = t + (slot << 8);
      const int il = c >> 6, jj = c & 63;
      const int j = base + jj;
      if (jj < tc) {
        const bool ok = (j <= i0 + il + 16);
        float e[16];
        if (ok) {
          float ch[16];
#pragma unroll
          for (int g = 0; g < 16; ++g) ch[g] = sS[g * 513 + c];
#pragma unroll
          for (int g2 = 0; g2 < 16; ++g2) {
            const float4* wr = (const float4*)&sWpre[g2 << 4];
            float4 w0 = wr[0], w1 = wr[1], w2 = wr[2], w3 = wr[3];
            float mm = w0.x * ch[0] + w0.y * ch[1] + w0.z * ch[2] + w0.w * ch[3]
                     + w1.x * ch[4] + w1.y * ch[5] + w1.z * ch[6] + w1.w * ch[7]
                     + w2.x * ch[8] + w2.y * ch[9] + w2.z * ch[10] + w2.w * ch[11]
                     + w3.x * ch[12] + w3.y * ch[13] + w3.z * ch[14] + w3.w * ch[15];
            e[g2] = __expf(mm - 20.f) * sIL[(il << 4) + g2];
          }
        } else {
#pragma unroll
          for (int g = 0; g < 16; ++g) e[g] = 0.f;
        }
#pragma unroll
        for (int g2 = 0; g2 < 16; ++g2) {
          const float4* wr = (const float4*)&sWpost[g2 << 4];
          float4 w0 = wr[0], w1 = wr[1], w2 = wr[2], w3 = wr[3];
          float p = w0.x * e[0] + w0.y * e[1] + w0.z * e[2] + w0.w * e[3]
                  + w1.x * e[4] + w1.y * e[5] + w1.z * e[6] + w1.w * e[7]
                  + w2.x * e[8] + w2.y * e[9] + w2.z * e[10] + w2.w * e[11]
                  + w3.x * e[12] + w3.y * e[13] + w3.z * e[14] + w3.w * e[15];
          sS[g2 * 513 + c] = p;
        }
      }
    }
    __syncthreads();
#pragma unroll 4
    for (int jj = 0; jj < tc; ++jj) {
      const int j = base + jj;
      const uint4* vp = (const uint4*)(vall + (((size_t)(b * 1040 + j)) << 10) + (lane << 4));
      uint4 v0 = vp[0], v1 = vp[1];
      float vf[16];
      vf[0] = bf_lo(v0.x); vf[1] = bf_hi(v0.x); vf[2] = bf_lo(v0.y); vf[3] = bf_hi(v0.y);
      vf[4] = bf_lo(v0.z); vf[5] = bf_hi(v0.z); vf[6] = bf_lo(v0.w); vf[7] = bf_hi(v0.w);
      vf[8] = bf_lo(v1.x); vf[9] = bf_hi(v1.x); vf[10] = bf_lo(v1.y); vf[11] = bf_hi(v1.y);
      vf[12] = bf_lo(v1.z); vf[13] = bf_hi(v1.z); vf[14] = bf_lo(v1.w); vf[15] = bf_hi(v1.w);
#pragma unroll
      for (int ii = 0; ii < 2; ++ii) {
        float p = sS[(lane >> 2) * 513 + ((w + (ii << 2)) << 6) + jj];
#pragma unroll
        for (int u = 0; u < 4; ++u) {
          vacc[ii][u].x += p * vf[u * 4 + 0];
          vacc[ii][u].y += p * vf[u * 4 + 1];
          vacc[ii][u].z += p * vf[u * 4 + 2];
          vacc[ii][u].w += p * vf[u * 4 + 3];
        }
      }
    }
  }

  // gates + atomic accumulation of this split's partial
#pragma unroll
  for (int ii = 0; ii < 2; ++ii) {
    const int irow = (b << 10) + i0 + w + (ii << 2);
    const float hg = hgate[irow * 16 + (lane >> 2)];
    const float4* vg = (const float4*)(vgate + ((size_t)irow << 10) + (lane << 4));
    float* op = aobuf + ((size_t)irow << 10) + (lane << 4);
#pragma unroll
    for (int u = 0; u < 4; ++u) {
      float4 g = vg[u];
      atomicAdd(op + u * 4 + 0, vacc[ii][u].x * hg * g.x);
      atomicAdd(op + u * 4 + 1, vacc[ii][u].y * hg * g.y);
      atomicAdd(op + u * 4 + 2, vacc[ii][u].z * hg * g.z);
      atomicAdd(op + u * 4 + 3, vacc[ii][u].w * hg * g.w);
    }
  }
}

extern "C" void kernel_launch(void* const* d_in, const int* in_sizes, int n_in,
                              void* d_out, int out_size, void* d_ws, size_t ws_size,
                              hipStream_t stream)
{
  const float* x       = (const float*)d_in[0];
  const float* freqs   = (const float*)d_in[1];
  const float* Wq      = (const float*)d_in[2];
  const float* Wk      = (const float*)d_in[3];
  const float* Wv      = (const float*)d_in[4];
  const float* q_scale = (const float*)d_in[5];
  const float* k_scale = (const float*)d_in[6];
  const float* mem_k   = (const float*)d_in[7];
  const float* mem_v   = (const float*)d_in[8];
  const float* W_pre   = (const float*)d_in[9];
  const float* W_post  = (const float*)d_in[10];
  const float* W_hg    = (const float*)d_in[11];
  const float* b_hg    = (const float*)d_in[12];
  const float* W_vg    = (const float*)d_in[13];
  const float* b_vg    = (const float*)d_in[14];
  const float* Wo      = (const float*)d_in[15];
  float* out = (float*)d_out;
  float* ws  = (float*)d_ws;

  // workspace layout (float offsets); total 19,562,496 floats = 78.2 MiB
  float* q_lin = ws;                                        // [4096,1024] fp32
  unsigned short* aob = (unsigned short*)ws;                // bf16 alias, after attn
  float* k_lin = ws + 4194304;                              // [4096,1024] fp32
  float* aobuf = k_lin;                                     // alias, after k_post_bf
  float* vgbuf = ws + 8388608;                              // [4096,1024]
  float* hgbuf = ws + 12582912;                             // [4096,16]
  float* Lbuf  = ws + 12648448;                             // [4,1024,16]
  unsigned short* vall = (unsigned short*)(ws + 12713984);  // [4,1040,1024] bf16
  unsigned short* xb   = (unsigned short*)(ws + 14843904);  // [4096,1024] bf16
  unsigned short* kall = (unsigned short*)(ws + 14843904);  // alias xb+WqT, after gemms
  unsigned short* WqT  = (unsigned short*)(ws + 16941056);  // [1024,1024] bf16 each
  unsigned short* WkT  = (unsigned short*)(ws + 17465344);
  unsigned short* WvT  = (unsigned short*)(ws + 17989632);
  unsigned short* WvgT = (unsigned short*)(ws + 18513920);
  unsigned short* WoT  = (unsigned short*)(ws + 19038208);

  dim3 blk(256);
  // bf16 conversions / transposes
  cvt_bf16x4<<<4096, blk, 0, stream>>>(x, xb, 1048576);
  transpose_to_bf<<<dim3(16, 16), blk, 0, stream>>>(Wq, WqT);
  transpose_to_bf<<<dim3(16, 16), blk, 0, stream>>>(Wk, WkT);
  transpose_to_bf<<<dim3(16, 16), blk, 0, stream>>>(Wv, WvT);
  transpose_to_bf<<<dim3(16, 16), blk, 0, stream>>>(W_vg, WvgT);
  transpose_to_bf<<<dim3(16, 16), blk, 0, stream>>>(Wo, WoT);
  // head-gate projection (tiny, fp32 path)
  gemm_f32<<<dim3(1, 64), blk, 0, stream>>>(x, W_hg, hgbuf, 4096, 16, 1024);
  sigmoid_bias<<<256, blk, 0, stream>>>(hgbuf, b_hg, 65536, 15);
  // MFMA projections
  gemm_bf<<<dim3(16, 32), blk, 0, stream>>>(xb, WqT, q_lin, nullptr, 0);
  gemm_bf<<<dim3(16, 32), blk, 0, stream>>>(xb, WkT, k_lin, nullptr, 0);
  gemm_bf<<<dim3(16, 32), blk, 0, stream>>>(xb, WvT, nullptr, vall, 1);
  gemm_bf<<<dim3(16, 32), blk, 0, stream>>>(xb, WvgT, vgbuf, nullptr, 0);
  // postprocessing
  qk_post<<<16384, blk, 0, stream>>>(q_lin, q_scale, freqs);
  k_post_bf<<<16384, blk, 0, stream>>>(k_lin, k_scale, freqs, kall);
  mem_build<<<64, blk, 0, stream>>>(mem_k, mem_v, k_scale, kall, vall);
  sigmoid_bias<<<16384, blk, 0, stream>>>(vgbuf, b_vg, 4194304, 1023);
  // zero accumulators (stream-ordered; aobuf reuses k_lin which is now dead)
  hipMemsetAsync(Lbuf, 0, 65536 * sizeof(float), stream);
  hipMemsetAsync(aobuf, 0, 4194304 * sizeof(float), stream);
  // attention: denominators, then gated PV accumulation
  attn_denom<<<2048, blk, 0, stream>>>(q_lin, kall, W_pre, Lbuf);
  attn_pv<<<2048, blk, 0, stream>>>(q_lin, kall, vall, W_pre, W_post,
                                    hgbuf, vgbuf, Lbuf, aobuf);
  // output projection
  cvt_bf16x4<<<4096, blk, 0, stream>>>(aobuf, aob, 1048576);
  gemm_bf<<<dim3(16, 32), blk, 0, stream>>>(aob, WoT, out, nullptr, 0);
}

// Round 4
// 809.155 us; speedup vs baseline: 3.3450x; 1.9653x over previous
//
#include <hip/hip_runtime.h>
#include <hip/hip_bf16.h>
#include <cmath>

// B=4, N=1024, DIM=1024, H=16, DH=64, M=16, QK_SCALE=10
typedef __attribute__((ext_vector_type(8))) short short8;
typedef __attribute__((ext_vector_type(4))) float f32x4;

__device__ __forceinline__ unsigned short to_bf(float f) {
  __hip_bfloat16 h = __float2bfloat16(f);
  return __builtin_bit_cast(unsigned short, h);
}

#define SIDX(h, i, j) (((h)*16 + (i))*17 + (j))      // fp32 S tile [16h][16i][17]
#define P2IDX(g, i, k) (((g)*16 + (i))*40 + (k))     // bf16 p2 tile [16g][16i][40]

// ---------------- fp32 GEMM (tiny hgate projection only) -------------------
__global__ __launch_bounds__(256)
void gemm_f32(const float* __restrict__ A, const float* __restrict__ Bm,
              float* __restrict__ C, int Mm, int N, int K)
{
  __shared__ float As[16][68];
  __shared__ float Bs[16][68];
  const int t = threadIdx.x;
  const int tx = t & 15, ty = t >> 4;
  const int row0 = blockIdx.y * 64, col0 = blockIdx.x * 64;
  float acc[4][4];
#pragma unroll
  for (int i = 0; i < 4; ++i)
#pragma unroll
    for (int j = 0; j < 4; ++j) acc[i][j] = 0.f;

  for (int kk = 0; kk < K; kk += 16) {
#pragma unroll
    for (int q = 0; q < 4; ++q) {
      int idx = t + q * 256;
      int c = idx & 15, r = idx >> 4;
      As[c][r] = A[(size_t)(row0 + r) * K + kk + c];
    }
#pragma unroll
    for (int q = 0; q < 4; ++q) {
      int idx = t + q * 256;
      int cb = idx & 63, rb = idx >> 6;
      int col = col0 + cb;
      Bs[rb][cb] = (col < N) ? Bm[(size_t)(kk + rb) * N + col] : 0.f;
    }
    __syncthreads();
#pragma unroll
    for (int k2 = 0; k2 < 16; ++k2) {
      float4 a4 = *(const float4*)&As[k2][ty << 2];
      float4 b4 = *(const float4*)&Bs[k2][tx << 2];
      float a[4] = {a4.x, a4.y, a4.z, a4.w};
      float b[4] = {b4.x, b4.y, b4.z, b4.w};
#pragma unroll
      for (int i = 0; i < 4; ++i)
#pragma unroll
        for (int j = 0; j < 4; ++j) acc[i][j] += a[i] * b[j];
    }
    __syncthreads();
  }
#pragma unroll
  for (int i = 0; i < 4; ++i) {
    int row = row0 + (ty << 2) + i;
#pragma unroll
    for (int j = 0; j < 4; ++j) {
      int col = col0 + (tx << 2) + j;
      if (col < N) C[(size_t)row * N + col] = acc[i][j];
    }
  }
}

// -------- fp32 -> bf16 elementwise ------------------------------------------
__global__ __launch_bounds__(256)
void cvt_bf16x4(const float* __restrict__ in, unsigned short* __restrict__ out, int n4)
{
  int i = blockIdx.x * 256 + threadIdx.x;
  if (i < n4) {
    float4 v = ((const float4*)in)[i];
    ushort4 o;
    o.x = to_bf(v.x); o.y = to_bf(v.y); o.z = to_bf(v.z); o.w = to_bf(v.w);
    ((ushort4*)out)[i] = o;
  }
}

// -------- W [1024 k][1024 n] fp32 -> WT [n][k] bf16 -------------------------
__global__ __launch_bounds__(256)
void transpose_to_bf(const float* __restrict__ W, unsigned short* __restrict__ WT)
{
  __shared__ float tile[64][65];
  const int n0 = blockIdx.x * 64, k0 = blockIdx.y * 64;
  const int t = threadIdx.x, c = t & 63, r4 = t >> 6;
#pragma unroll
  for (int q = 0; q < 16; ++q) {
    int r = (q << 2) + r4;
    tile[r][c] = W[(size_t)(k0 + r) * 1024 + n0 + c];
  }
  __syncthreads();
#pragma unroll
  for (int q = 0; q < 16; ++q) {
    int r = (q << 2) + r4;
    WT[(size_t)(n0 + r) * 1024 + k0 + c] = to_bf(tile[c][r]);
  }
}

// -------- bf16 MFMA GEMM: 128x64 tile, BK=32. mode0: fp32 C; mode1: vallT ---
__global__ __launch_bounds__(256)
void gemm_bf(const unsigned short* __restrict__ A, const unsigned short* __restrict__ BT,
             float* __restrict__ C, unsigned short* __restrict__ Vout, int mode)
{
  __shared__ __align__(16) unsigned short Abuf[128 * 32];
  __shared__ __align__(16) unsigned short Bbuf[64 * 32];
  const int t = threadIdx.x, lane = t & 63, w = t >> 6;
  const int wm = w & 1, wn = w >> 1;
  const int col0 = blockIdx.x * 64, row0 = blockIdx.y * 128;

  f32x4 acc[4][2];
#pragma unroll
  for (int mi = 0; mi < 4; ++mi)
#pragma unroll
    for (int ni = 0; ni < 2; ++ni) acc[mi][ni] = (f32x4){0.f, 0.f, 0.f, 0.f};

  for (int kk = 0; kk < 1024; kk += 32) {
#pragma unroll
    for (int q = 0; q < 2; ++q) {
      int c = (q << 8) + t;
      int r = c >> 2, kp = c & 3;
      uint4 val = *(const uint4*)(A + (size_t)(row0 + r) * 1024 + kk + kp * 8);
      *(uint4*)((char*)Abuf + c * 16) = val;
    }
    {
      int c = t;
      int r = c >> 2, kp = c & 3;
      uint4 val = *(const uint4*)(BT + (size_t)(col0 + r) * 1024 + kk + kp * 8);
      *(uint4*)((char*)Bbuf + c * 16) = val;
    }
    __syncthreads();
    short8 af[4], bfr[2];
#pragma unroll
    for (int mi = 0; mi < 4; ++mi)
      af[mi] = *(const short8*)((char*)Abuf + ((wm << 6) + (mi << 4) + (lane & 15)) * 64 + (lane >> 4) * 16);
#pragma unroll
    for (int ni = 0; ni < 2; ++ni)
      bfr[ni] = *(const short8*)((char*)Bbuf + ((wn << 5) + (ni << 4) + (lane & 15)) * 64 + (lane >> 4) * 16);
#pragma unroll
    for (int mi = 0; mi < 4; ++mi)
#pragma unroll
      for (int ni = 0; ni < 2; ++ni)
        acc[mi][ni] = __builtin_amdgcn_mfma_f32_16x16x32_bf16(af[mi], bfr[ni], acc[mi][ni], 0, 0, 0);
    __syncthreads();
  }

  // C/D layout: col = lane&15, row = (lane>>4)*4 + reg
#pragma unroll
  for (int mi = 0; mi < 4; ++mi)
#pragma unroll
    for (int ni = 0; ni < 2; ++ni)
#pragma unroll
      for (int reg = 0; reg < 4; ++reg) {
        int m = row0 + (wm << 6) + (mi << 4) + ((lane >> 4) << 2) + reg;
        int n = col0 + (wn << 5) + (ni << 4) + (lane & 15);
        float v = acc[mi][ni][reg];
        if (mode == 0) {
          C[((size_t)m << 10) + n] = v;
        } else {
          int b = m >> 10, nn = m & 1023;        // V^T: vallT[b][hd=n][16+nn]
          Vout[((size_t)((b << 10) + n)) * 1056 + 16 + nn] = to_bf(v);
        }
      }
}

// ------ q post: l2norm * scale * QK_SCALE + rope -> bf16 qb -----------------
__global__ __launch_bounds__(256)
void q_post_bf(const float* __restrict__ q_lin, const float* __restrict__ scale,
               const float* __restrict__ freqs, unsigned short* __restrict__ qb)
{
  int gid = blockIdx.x * 256 + threadIdx.x;
  int d = gid & 63;
  int row = gid >> 6;
  int h = row & 15;
  int n = (row >> 4) & 1023;
  float v = q_lin[gid];
  float ss = v * v;
#pragma unroll
  for (int off = 32; off; off >>= 1) ss += __shfl_xor(ss, off);
  v = v / fmaxf(sqrtf(ss), 1e-12f) * scale[(h << 6) + d];
  float f = freqs[(n << 6) + d];
  float other = __shfl_xor(v, 1);
  float rot = (d & 1) ? other : -other;
  qb[gid] = to_bf((v * cosf(f) + rot * sinf(f)) * 10.f);   // QK_SCALE folded
}

// ------ k post: l2norm*scale + rope, write bf16 into kall (stride 1056) -----
__global__ __launch_bounds__(256)
void k_post_bf(const float* __restrict__ k_lin, const float* __restrict__ scale,
               const float* __restrict__ freqs, unsigned short* __restrict__ kall)
{
  int gid = blockIdx.x * 256 + threadIdx.x;
  int d = gid & 63;
  int row = gid >> 6;
  int h = row & 15;
  int n = (row >> 4) & 1023;
  int b = row >> 14;
  float v = k_lin[gid];
  float ss = v * v;
#pragma unroll
  for (int off = 32; off; off >>= 1) ss += __shfl_xor(ss, off);
  v = v / fmaxf(sqrtf(ss), 1e-12f) * scale[(h << 6) + d];
  float f = freqs[(n << 6) + d];
  float other = __shfl_xor(v, 1);
  float rot = (d & 1) ? other : -other;
  float out = v * cosf(f) + rot * sinf(f);
  kall[(size_t)(b * 1056 + 16 + n) * 1024 + (h << 6) + d] = to_bf(out);
}

// ------ memory slots into kall rows 0..15 and vallT cols 0..15 --------------
__global__ __launch_bounds__(256)
void mem_build(const float* __restrict__ mem_k, const float* __restrict__ mem_v,
               const float* __restrict__ k_scale,
               unsigned short* __restrict__ kall, unsigned short* __restrict__ vallT)
{
  int gid = blockIdx.x * 256 + threadIdx.x;   // 16384 = H*M*64
  int d = gid & 63;
  int row = gid >> 6;            // h*M + m
  int h = row >> 4, m = row & 15;
  float v = mem_k[gid];
  float ss = v * v;
#pragma unroll
  for (int off = 32; off; off >>= 1) ss += __shfl_xor(ss, off);
  unsigned short kb = to_bf(v / fmaxf(sqrtf(ss), 1e-12f) * k_scale[(h << 6) + d]);
  unsigned short vb = to_bf(mem_v[gid]);
#pragma unroll
  for (int b = 0; b < 4; ++b) {
    kall[(size_t)(b * 1056 + m) * 1024 + (h << 6) + d] = kb;
    vallT[(size_t)((b << 10) + (h << 6) + d) * 1056 + m] = vb;
  }
}

// ------------- sigmoid(x + bias[idx & mask]) in place -----------------------
__global__ __launch_bounds__(256)
void sigmoid_bias(float* __restrict__ x, const float* __restrict__ bias,
                  int n, int mask)
{
  int idx = blockIdx.x * 256 + threadIdx.x;
  if (idx < n) {
    float v = x[idx] + bias[idx & mask];
    x[idx] = 1.f / (1.f + __expf(-v));
  }
}

// ================= MFMA attention, talking heads, j-split ===================
// Block = (b, 16-query tile it, split s of 4). Wave w owns heads 4w..4w+3 for
// QK, and output heads g2 = 4w..4w+3 for PV. Logits bounded -> exp(m-20),
// additive partial denominators (pass 1), PV partials atomicAdd (pass 2).

// ---- pass 1: partial denominators -> atomicAdd Lbuf[b][i][g] ---------------
__global__ __launch_bounds__(256)
void attn_denom(const unsigned short* __restrict__ qb, const unsigned short* __restrict__ kall,
                const float* __restrict__ W_pre, float* __restrict__ Lbuf)
{
  __shared__ float sS[16 * 16 * 17];
  __shared__ float sWpre[256];
  __shared__ float sL[256];     // [i][g]

  const int t = threadIdx.x, lane = t & 63, w = t >> 6;
  const int raw = blockIdx.x;
  const int b = raw & 3, it = (raw >> 2) & 63, s = raw >> 8;
  const int i0 = it << 4;
  const int T = it + 2;                      // 16-j tiles (jmax = i0+32)
  const int t0 = (T * s) >> 2, t1 = (T * (s + 1)) >> 2;
  if (t0 == t1) return;

  sWpre[t] = W_pre[t];
  sL[t] = 0.f;

  const int m = lane & 15, quad = lane >> 4;
  // A-frags: q[b][i0+m][h*64 + kk*32 + quad*8 ..+7], heads 4w..4w+3
  short8 afr[4][2];
#pragma unroll
  for (int hh = 0; hh < 4; ++hh)
#pragma unroll
    for (int kk = 0; kk < 2; ++kk)
      afr[hh][kk] = *(const short8*)(qb + (((size_t)(b << 10) + i0 + m) << 10)
                                     + ((w << 2) + hh) * 64 + kk * 32 + quad * 8);

  for (int tt = t0; tt < t1; ++tt) {
    const int j0 = tt << 4;
    // QK: wave computes S for its 4 heads
#pragma unroll
    for (int hh = 0; hh < 4; ++hh) {
      f32x4 acc = (f32x4){0.f, 0.f, 0.f, 0.f};
#pragma unroll
      for (int kk = 0; kk < 2; ++kk) {
        short8 bfr = *(const short8*)(kall + ((size_t)(b * 1056 + j0 + m) << 10)
                                      + ((w << 2) + hh) * 64 + kk * 32 + quad * 8);
        acc = __builtin_amdgcn_mfma_f32_16x16x32_bf16(afr[hh][kk], bfr, acc, 0, 0, 0);
      }
#pragma unroll
      for (int reg = 0; reg < 4; ++reg)
        sS[SIDX((w << 2) + hh, (quad << 2) + reg, m)] = acc[reg];
    }
    __syncthreads();
    // premix + exp + j-reduce
    {
      const int i_l = t >> 4, j_l = t & 15;
      const bool ok = (j0 + j_l) <= (i0 + i_l + 16);
      float ch[16];
#pragma unroll
      for (int h = 0; h < 16; ++h) ch[h] = sS[SIDX(h, i_l, j_l)];
      float e[16];
#pragma unroll
      for (int g = 0; g < 16; ++g) {
        float mm = 0.f;
#pragma unroll
        for (int h = 0; h < 16; ++h) mm += sWpre[(g << 4) + h] * ch[h];
        e[g] = ok ? __expf(mm - 20.f) : 0.f;
      }
#pragma unroll
      for (int g = 0; g < 16; ++g) {
        float v = e[g];
        v += __shfl_xor(v, 1); v += __shfl_xor(v, 2);
        v += __shfl_xor(v, 4); v += __shfl_xor(v, 8);
        if (j_l == 0) sL[(i_l << 4) + g] += v;
      }
    }
    __syncthreads();
  }
  atomicAdd(&Lbuf[(((size_t)(b << 10) + i0 + (t >> 4)) << 4) + (t & 15)], sL[t]);
}

// ---- pass 2: recompute, normalize, post-mix, MFMA PV, gated atomic out -----
__global__ __launch_bounds__(256)
void attn_pv(const unsigned short* __restrict__ qb, const unsigned short* __restrict__ kall,
             const unsigned short* __restrict__ vallT, const float* __restrict__ W_pre,
             const float* __restrict__ W_post, const float* __restrict__ hgate,
             const float* __restrict__ vgate, const float* __restrict__ Lbuf,
             float* __restrict__ aobuf)
{
  __shared__ float sS[16 * 16 * 17];
  __shared__ unsigned short p2L[16 * 16 * 40];
  __shared__ float sWpre[256], sWpost[256], sIL[256];

  const int t = threadIdx.x, lane = t & 63, w = t >> 6;
  const int raw = blockIdx.x;
  const int b = raw & 3, it = (raw >> 2) & 63, s = raw >> 8;
  const int i0 = it << 4;
  const int U = (i0 + 63) >> 5;              // 32-j units (jmax = i0+32)
  const int u0 = (U * s) >> 2, u1 = (U * (s + 1)) >> 2;
  if (u0 == u1) return;

  sWpre[t] = W_pre[t];
  sWpost[t] = W_post[t];
  sIL[t] = 1.f / Lbuf[(((size_t)(b << 10) + i0 + (t >> 4)) << 4) + (t & 15)];

  const int m = lane & 15, quad = lane >> 4;
  short8 afr[4][2];
#pragma unroll
  for (int hh = 0; hh < 4; ++hh)
#pragma unroll
    for (int kk = 0; kk < 2; ++kk)
      afr[hh][kk] = *(const short8*)(qb + (((size_t)(b << 10) + i0 + m) << 10)
                                     + ((w << 2) + hh) * 64 + kk * 32 + quad * 8);

  f32x4 oacc[4][4];                          // [g2 local][d-tile]
#pragma unroll
  for (int a = 0; a < 4; ++a)
#pragma unroll
    for (int dt = 0; dt < 4; ++dt) oacc[a][dt] = (f32x4){0.f, 0.f, 0.f, 0.f};

  for (int u = u0; u < u1; ++u) {
    const int j0 = u << 5;
#pragma unroll
    for (int sub = 0; sub < 2; ++sub) {
      const int js = j0 + (sub << 4);
      // QK
#pragma unroll
      for (int hh = 0; hh < 4; ++hh) {
        f32x4 acc = (f32x4){0.f, 0.f, 0.f, 0.f};
#pragma unroll
        for (int kk = 0; kk < 2; ++kk) {
          short8 bfr = *(const short8*)(kall + ((size_t)(b * 1056 + js + m) << 10)
                                        + ((w << 2) + hh) * 64 + kk * 32 + quad * 8);
          acc = __builtin_amdgcn_mfma_f32_16x16x32_bf16(afr[hh][kk], bfr, acc, 0, 0, 0);
        }
#pragma unroll
        for (int reg = 0; reg < 4; ++reg)
          sS[SIDX((w << 2) + hh, (quad << 2) + reg, m)] = acc[reg];
      }
      __syncthreads();
      // premix + normalize + postmix -> p2L (bf16, A-layout k-slot sub*16+j)
      {
        const int i_l = t >> 4, j_l = t & 15;
        const bool ok = (js + j_l) <= (i0 + i_l + 16);
        float ch[16];
#pragma unroll
        for (int h = 0; h < 16; ++h) ch[h] = sS[SIDX(h, i_l, j_l)];
        float e[16];
#pragma unroll
        for (int g = 0; g < 16; ++g) {
          float mm = 0.f;
#pragma unroll
          for (int h = 0; h < 16; ++h) mm += sWpre[(g << 4) + h] * ch[h];
          e[g] = ok ? __expf(mm - 20.f) * sIL[(i_l << 4) + g] : 0.f;
        }
#pragma unroll
        for (int g2 = 0; g2 < 16; ++g2) {
          float p = 0.f;
#pragma unroll
          for (int g = 0; g < 16; ++g) p += sWpost[(g2 << 4) + g] * e[g];
          p2L[P2IDX(g2, i_l, (sub << 4) + j_l)] = to_bf(p);
        }
      }
      __syncthreads();
    }
    // PV over the 32-j unit: wave w handles g2 = 4w..4w+3
#pragma unroll
    for (int g2l = 0; g2l < 4; ++g2l) {
      const int g2 = (w << 2) + g2l;
      short8 a = *(const short8*)((char*)p2L + (P2IDX(g2, m, quad * 8)) * 2);
#pragma unroll
      for (int dt = 0; dt < 4; ++dt) {
        short8 bv = *(const short8*)(vallT + ((size_t)((b << 10) + g2 * 64 + dt * 16 + m)) * 1056
                                     + j0 + quad * 8);
        oacc[g2l][dt] = __builtin_amdgcn_mfma_f32_16x16x32_bf16(a, bv, oacc[g2l][dt], 0, 0, 0);
      }
    }
  }

  // epilogue: gates + atomic accumulation. C layout: row i = quad*4+reg, col d = dt*16 + m
#pragma unroll
  for (int g2l = 0; g2l < 4; ++g2l) {
    const int g2 = (w << 2) + g2l;
#pragma unroll
    for (int reg = 0; reg < 4; ++reg) {
      const int irow = (b << 10) + i0 + (quad << 2) + reg;
      const float hg = hgate[irow * 16 + g2];
#pragma unroll
      for (int dt = 0; dt < 4; ++dt) {
        const int colg = g2 * 64 + dt * 16 + m;
        const float vg = vgate[((size_t)irow << 10) + colg];
        atomicAdd(&aobuf[((size_t)irow << 10) + colg], oacc[g2l][dt][reg] * hg * vg);
      }
    }
  }
}

extern "C" void kernel_launch(void* const* d_in, const int* in_sizes, int n_in,
                              void* d_out, int out_size, void* d_ws, size_t ws_size,
                              hipStream_t stream)
{
  const float* x       = (const float*)d_in[0];
  const float* freqs   = (const float*)d_in[1];
  const float* Wq      = (const float*)d_in[2];
  const float* Wk      = (const float*)d_in[3];
  const float* Wv      = (const float*)d_in[4];
  const float* q_scale = (const float*)d_in[5];
  const float* k_scale = (const float*)d_in[6];
  const float* mem_k   = (const float*)d_in[7];
  const float* mem_v   = (const float*)d_in[8];
  const float* W_pre   = (const float*)d_in[9];
  const float* W_post  = (const float*)d_in[10];
  const float* W_hg    = (const float*)d_in[11];
  const float* b_hg    = (const float*)d_in[12];
  const float* W_vg    = (const float*)d_in[13];
  const float* b_vg    = (const float*)d_in[14];
  const float* Wo      = (const float*)d_in[15];
  float* out = (float*)d_out;
  float* ws  = (float*)d_ws;

  // workspace layout (float offsets), total 19,660,800 f = 75.0 MiB
  float* q_lin = ws;                                        // [4096,1024]; -> aobuf
  float* aobuf = q_lin;
  float* k_lin = ws + 4194304;                              // [4096,1024]; -> aob
  unsigned short* aob = (unsigned short*)k_lin;
  float* vgbuf = ws + 8388608;                              // [4096,1024]
  float* hgbuf = ws + 12582912;                             // [4096,16]
  float* Lbuf  = ws + 12648448;                             // [4,1024,16]
  unsigned short* xb   = (unsigned short*)(ws + 12713984);  // [4096,1024] bf16; -> qb
  unsigned short* qb   = xb;
  unsigned short* kall = (unsigned short*)(ws + 14811136);  // [4,1056,1024] bf16
  unsigned short* vallT= (unsigned short*)(ws + 16973824);  // [4,1024,1056] bf16
  unsigned short* wb   = (unsigned short*)(ws + 19136512);  // [1024,1024] bf16 (reused)

  dim3 blk(256);
  cvt_bf16x4<<<4096, blk, 0, stream>>>(x, xb, 1048576);
  // head-gate projection (fp32 path, reads original x)
  gemm_f32<<<dim3(1, 64), blk, 0, stream>>>(x, W_hg, hgbuf, 4096, 16, 1024);
  sigmoid_bias<<<256, blk, 0, stream>>>(hgbuf, b_hg, 65536, 15);
  // MFMA projections (weight transpose buffer reused serially)
  transpose_to_bf<<<dim3(16, 16), blk, 0, stream>>>(Wq, wb);
  gemm_bf<<<dim3(16, 32), blk, 0, stream>>>(xb, wb, q_lin, nullptr, 0);
  transpose_to_bf<<<dim3(16, 16), blk, 0, stream>>>(Wk, wb);
  gemm_bf<<<dim3(16, 32), blk, 0, stream>>>(xb, wb, k_lin, nullptr, 0);
  transpose_to_bf<<<dim3(16, 16), blk, 0, stream>>>(Wv, wb);
  gemm_bf<<<dim3(16, 32), blk, 0, stream>>>(xb, wb, nullptr, vallT, 1);
  transpose_to_bf<<<dim3(16, 16), blk, 0, stream>>>(W_vg, wb);
  gemm_bf<<<dim3(16, 32), blk, 0, stream>>>(xb, wb, vgbuf, nullptr, 0);
  sigmoid_bias<<<16384, blk, 0, stream>>>(vgbuf, b_vg, 4194304, 1023);
  // q/k/mem postprocessing (qb overwrites xb — all xb readers are done)
  q_post_bf<<<16384, blk, 0, stream>>>(q_lin, q_scale, freqs, qb);
  k_post_bf<<<16384, blk, 0, stream>>>(k_lin, k_scale, freqs, kall);
  mem_build<<<64, blk, 0, stream>>>(mem_k, mem_v, k_scale, kall, vallT);
  // zero accumulators (q_lin/k_lin dead by now)
  hipMemsetAsync(Lbuf, 0, 65536 * sizeof(float), stream);
  hipMemsetAsync(aobuf, 0, 4194304 * sizeof(float), stream);
  // attention
  attn_denom<<<1024, blk, 0, stream>>>(qb, kall, W_pre, Lbuf);
  attn_pv<<<1024, blk, 0, stream>>>(qb, kall, vallT, W_pre, W_post,
                                    hgbuf, vgbuf, Lbuf, aobuf);
  // output projection
  cvt_bf16x4<<<4096, blk, 0, stream>>>(aobuf, aob, 1048576);
  transpose_to_bf<<<dim3(16, 16), blk, 0, stream>>>(Wo, wb);
  gemm_bf<<<dim3(16, 32), blk, 0, stream>>>(aob, wb, out, nullptr, 0);
}

// Round 7
// 619.706 us; speedup vs baseline: 4.3676x; 1.3057x over previous
//
#include <hip/hip_runtime.h>
#include <hip/hip_bf16.h>
#include <cmath>

// B=4, N=1024, DIM=1024, H=16, DH=64, M=16, QK_SCALE=10
typedef __attribute__((ext_vector_type(8))) short short8;
typedef __attribute__((ext_vector_type(4))) float f32x4;

__device__ __forceinline__ unsigned short to_bf(float f) {
  __hip_bfloat16 h = __float2bfloat16(f);
  return __builtin_bit_cast(unsigned short, h);
}

// ---------------- fp32 GEMM (tiny hgate projection only) -------------------
__global__ __launch_bounds__(256)
void gemm_f32(const float* __restrict__ A, const float* __restrict__ Bm,
              float* __restrict__ C, int Mm, int N, int K)
{
  __shared__ float As[16][68];
  __shared__ float Bs[16][68];
  const int t = threadIdx.x;
  const int tx = t & 15, ty = t >> 4;
  const int row0 = blockIdx.y * 64, col0 = blockIdx.x * 64;
  float acc[4][4];
#pragma unroll
  for (int i = 0; i < 4; ++i)
#pragma unroll
    for (int j = 0; j < 4; ++j) acc[i][j] = 0.f;

  for (int kk = 0; kk < K; kk += 16) {
#pragma unroll
    for (int q = 0; q < 4; ++q) {
      int idx = t + q * 256;
      int c = idx & 15, r = idx >> 4;
      As[c][r] = A[(size_t)(row0 + r) * K + kk + c];
    }
#pragma unroll
    for (int q = 0; q < 4; ++q) {
      int idx = t + q * 256;
      int cb = idx & 63, rb = idx >> 6;
      int col = col0 + cb;
      Bs[rb][cb] = (col < N) ? Bm[(size_t)(kk + rb) * N + col] : 0.f;
    }
    __syncthreads();
#pragma unroll
    for (int k2 = 0; k2 < 16; ++k2) {
      float4 a4 = *(const float4*)&As[k2][ty << 2];
      float4 b4 = *(const float4*)&Bs[k2][tx << 2];
      float a[4] = {a4.x, a4.y, a4.z, a4.w};
      float b[4] = {b4.x, b4.y, b4.z, b4.w};
#pragma unroll
      for (int i = 0; i < 4; ++i)
#pragma unroll
        for (int j = 0; j < 4; ++j) acc[i][j] += a[i] * b[j];
    }
    __syncthreads();
  }
#pragma unroll
  for (int i = 0; i < 4; ++i) {
    int row = row0 + (ty << 2) + i;
#pragma unroll
    for (int j = 0; j < 4; ++j) {
      int col = col0 + (tx << 2) + j;
      if (col < N) C[(size_t)row * N + col] = acc[i][j];
    }
  }
}

// -------- fp32 -> bf16 elementwise ------------------------------------------
__global__ __launch_bounds__(256)
void cvt_bf16x4(const float* __restrict__ in, unsigned short* __restrict__ out, int n4)
{
  int i = blockIdx.x * 256 + threadIdx.x;
  if (i < n4) {
    float4 v = ((const float4*)in)[i];
    ushort4 o;
    o.x = to_bf(v.x); o.y = to_bf(v.y); o.z = to_bf(v.z); o.w = to_bf(v.w);
    ((ushort4*)out)[i] = o;
  }
}

// -------- W [1024 k][1024 n] fp32 -> WT [n][k] bf16 -------------------------
__global__ __launch_bounds__(256)
void transpose_to_bf(const float* __restrict__ W, unsigned short* __restrict__ WT)
{
  __shared__ float tile[64][65];
  const int n0 = blockIdx.x * 64, k0 = blockIdx.y * 64;
  const int t = threadIdx.x, c = t & 63, r4 = t >> 6;
#pragma unroll
  for (int q = 0; q < 16; ++q) {
    int r = (q << 2) + r4;
    tile[r][c] = W[(size_t)(k0 + r) * 1024 + n0 + c];
  }
  __syncthreads();
#pragma unroll
  for (int q = 0; q < 16; ++q) {
    int r = (q << 2) + r4;
    WT[(size_t)(n0 + r) * 1024 + k0 + c] = to_bf(tile[c][r]);
  }
}

// ---- bf16 MFMA GEMM, 128x128 tile, BK=32, stride-80 LDS (conflict-free) ----
// mode 0: fp32 C[m][n]; mode 1: bf16 V^T into vallT[b][n][16+nn].
__global__ __launch_bounds__(256)
void gemm_bf128(const unsigned short* __restrict__ A, const unsigned short* __restrict__ BT,
                float* __restrict__ C, unsigned short* __restrict__ Vout, int mode)
{
  __shared__ __align__(16) unsigned short Ab[128 * 40];
  __shared__ __align__(16) unsigned short Bb[128 * 40];
  const int t = threadIdx.x, lane = t & 63, w = t >> 6;
  const int m = lane & 15, quad = lane >> 4;
  const int wm = w & 1, wn = w >> 1;
  const int row0 = blockIdx.y << 7, col0 = blockIdx.x << 7;

  f32x4 acc[4][4];
#pragma unroll
  for (int mi = 0; mi < 4; ++mi)
#pragma unroll
    for (int ni = 0; ni < 4; ++ni) acc[mi][ni] = (f32x4){0.f, 0.f, 0.f, 0.f};

  for (int kk = 0; kk < 1024; kk += 32) {
#pragma unroll
    for (int q = 0; q < 2; ++q) {
      int c = t + (q << 8);
      int r = c >> 2, kp = c & 3;
      uint4 va = *(const uint4*)(A + (size_t)(row0 + r) * 1024 + kk + kp * 8);
      *(uint4*)((char*)Ab + r * 80 + kp * 16) = va;
      uint4 vb = *(const uint4*)(BT + (size_t)(col0 + r) * 1024 + kk + kp * 8);
      *(uint4*)((char*)Bb + r * 80 + kp * 16) = vb;
    }
    __syncthreads();
    short8 af[4], bf[4];
#pragma unroll
    for (int mi = 0; mi < 4; ++mi)
      af[mi] = *(const short8*)((char*)Ab + ((wm << 6) + (mi << 4) + m) * 80 + quad * 16);
#pragma unroll
    for (int ni = 0; ni < 4; ++ni)
      bf[ni] = *(const short8*)((char*)Bb + ((wn << 6) + (ni << 4) + m) * 80 + quad * 16);
#pragma unroll
    for (int mi = 0; mi < 4; ++mi)
#pragma unroll
      for (int ni = 0; ni < 4; ++ni)
        acc[mi][ni] = __builtin_amdgcn_mfma_f32_16x16x32_bf16(af[mi], bf[ni], acc[mi][ni], 0, 0, 0);
    __syncthreads();
  }
  // C/D layout: col = lane&15, row = quad*4 + reg
#pragma unroll
  for (int mi = 0; mi < 4; ++mi)
#pragma unroll
    for (int ni = 0; ni < 4; ++ni)
#pragma unroll
      for (int reg = 0; reg < 4; ++reg) {
        int mrow = row0 + (wm << 6) + (mi << 4) + (quad << 2) + reg;
        int ncol = col0 + (wn << 6) + (ni << 4) + m;
        float v = acc[mi][ni][reg];
        if (mode == 0) {
          C[((size_t)mrow << 10) + ncol] = v;
        } else {
          int bb = mrow >> 10, nn = mrow & 1023;
          Vout[((size_t)((bb << 10) + ncol)) * 1056 + 16 + nn] = to_bf(v);
        }
      }
}

// ------ q post: l2norm * scale * QK_SCALE + rope -> bf16 qb -----------------
__global__ __launch_bounds__(256)
void q_post_bf(const float* __restrict__ q_lin, const float* __restrict__ scale,
               const float* __restrict__ freqs, unsigned short* __restrict__ qb)
{
  int gid = blockIdx.x * 256 + threadIdx.x;
  int d = gid & 63;
  int row = gid >> 6;
  int h = row & 15;
  int n = (row >> 4) & 1023;
  float v = q_lin[gid];
  float ss = v * v;
#pragma unroll
  for (int off = 32; off; off >>= 1) ss += __shfl_xor(ss, off);
  v = v / fmaxf(sqrtf(ss), 1e-12f) * scale[(h << 6) + d];
  float f = freqs[(n << 6) + d];
  float other = __shfl_xor(v, 1);
  float rot = (d & 1) ? other : -other;
  qb[gid] = to_bf((v * cosf(f) + rot * sinf(f)) * 10.f);   // QK_SCALE folded
}

// ------ k post: l2norm*scale + rope, bf16 into kall (row stride 1056) -------
__global__ __launch_bounds__(256)
void k_post_bf(const float* __restrict__ k_lin, const float* __restrict__ scale,
               const float* __restrict__ freqs, unsigned short* __restrict__ kall)
{
  int gid = blockIdx.x * 256 + threadIdx.x;
  int d = gid & 63;
  int row = gid >> 6;
  int h = row & 15;
  int n = (row >> 4) & 1023;
  int b = row >> 14;
  float v = k_lin[gid];
  float ss = v * v;
#pragma unroll
  for (int off = 32; off; off >>= 1) ss += __shfl_xor(ss, off);
  v = v / fmaxf(sqrtf(ss), 1e-12f) * scale[(h << 6) + d];
  float f = freqs[(n << 6) + d];
  float other = __shfl_xor(v, 1);
  float rot = (d & 1) ? other : -other;
  float out = v * cosf(f) + rot * sinf(f);
  kall[(size_t)(b * 1056 + 16 + n) * 1024 + (h << 6) + d] = to_bf(out);
}

// ------ memory slots into kall rows 0..15 and vallT cols 0..15 --------------
__global__ __launch_bounds__(256)
void mem_build(const float* __restrict__ mem_k, const float* __restrict__ mem_v,
               const float* __restrict__ k_scale,
               unsigned short* __restrict__ kall, unsigned short* __restrict__ vallT)
{
  int gid = blockIdx.x * 256 + threadIdx.x;   // 16384 = H*M*64
  int d = gid & 63;
  int row = gid >> 6;            // h*M + mm
  int h = row >> 4, mm = row & 15;
  float v = mem_k[gid];
  float ss = v * v;
#pragma unroll
  for (int off = 32; off; off >>= 1) ss += __shfl_xor(ss, off);
  unsigned short kb = to_bf(v / fmaxf(sqrtf(ss), 1e-12f) * k_scale[(h << 6) + d]);
  unsigned short vb = to_bf(mem_v[gid]);
#pragma unroll
  for (int b = 0; b < 4; ++b) {
    kall[(size_t)(b * 1056 + mm) * 1024 + (h << 6) + d] = kb;
    vallT[(size_t)((b << 10) + (h << 6) + d) * 1056 + mm] = vb;
  }
}

// ------------- sigmoid(x + bias[idx & mask]) in place -----------------------
__global__ __launch_bounds__(256)
void sigmoid_bias(float* __restrict__ x, const float* __restrict__ bias,
                  int n, int mask)
{
  int idx = blockIdx.x * 256 + threadIdx.x;
  if (idx < n) {
    float v = x[idx] + bias[idx & mask];
    x[idx] = 1.f / (1.f + __expf(-v));
  }
}

// ================= two-pass MFMA attention, flat-balanced ===================
// W_post mixes NORMALIZED probs and V is indexed by the OUTPUT head, so the
// mix must happen per (i,j) column between normalize and PV (single-pass
// O_g/L_g factorization is WRONG - R6 bug). Pass 1 computes L (additive,
// bounded logits -> exp(m-20)); pass 2 normalizes, applies W_post, PV.
// Work = 4352 32-j units flat-split over the grid (perfect balance).

// ---- pass 1: denominators L[b][i][g] via atomicAdd -------------------------
__global__ __launch_bounds__(256)
void attn_lsum(const unsigned short* __restrict__ qb, const unsigned short* __restrict__ kall,
               const float* __restrict__ W_pre, float* __restrict__ Lbuf)
{
  __shared__ float sS[16 * 16 * 33];            // [h][i][j 0..31], stride 33
  __shared__ float sWpre[256];

  const int t = threadIdx.x, lane = t & 63, w = t >> 6;
  const int m = lane & 15, quad = lane >> 4;
  sWpre[t] = W_pre[t];

  const int blk = blockIdx.x;                   // grid 1024
  const int u0 = (4352 * blk) >> 10, u1 = (4352 * (blk + 1)) >> 10;
  if (u0 == u1) return;

  int accu = 0, bi = 0;
  while (true) {
    int un = (((bi & 63) + 1) >> 1) + 1;
    if (accu + un > u0) break;
    accu += un; ++bi;
  }
  int b = bi >> 6, it = bi & 63, uoff = u0 - accu;

  short8 afr[4][2];
  float partL[16];
  bool fresh = true;

  for (int u = u0; u < u1; ++u) {
    const int i0 = it << 4;
    if (fresh) {
#pragma unroll
      for (int hh = 0; hh < 4; ++hh)
#pragma unroll
        for (int kk = 0; kk < 2; ++kk)
          afr[hh][kk] = *(const short8*)(qb + (((size_t)(b << 10) + i0 + m) << 10)
                                         + ((w << 2) + hh) * 64 + kk * 32 + quad * 8);
#pragma unroll
      for (int g = 0; g < 16; ++g) partL[g] = 0.f;
      fresh = false;
    }
    const int j0 = uoff << 5;
#pragma unroll
    for (int sub = 0; sub < 2; ++sub) {
      const int js = j0 + (sub << 4);
#pragma unroll
      for (int hh = 0; hh < 4; ++hh) {
        f32x4 s = (f32x4){0.f, 0.f, 0.f, 0.f};
#pragma unroll
        for (int kk = 0; kk < 2; ++kk) {
          short8 bfr = *(const short8*)(kall + ((size_t)(b * 1056 + js + m) << 10)
                                        + ((w << 2) + hh) * 64 + kk * 32 + quad * 8);
          s = __builtin_amdgcn_mfma_f32_16x16x32_bf16(afr[hh][kk], bfr, s, 0, 0, 0);
        }
#pragma unroll
        for (int reg = 0; reg < 4; ++reg)
          sS[(((w << 2) + hh) * 16 + (quad << 2) + reg) * 33 + (sub << 4) + m] = s[reg];
      }
    }
    __syncthreads();
    {
      const int i_l = t >> 4, j_l = t & 15;
      const int ig = i0 + i_l;
      float ch0[16], ch1[16];
#pragma unroll
      for (int h = 0; h < 16; ++h) {
        ch0[h] = sS[(h * 16 + i_l) * 33 + j_l];
        ch1[h] = sS[(h * 16 + i_l) * 33 + 16 + j_l];
      }
      const bool ok0 = (j0 + j_l) <= ig + 16;
      const bool ok1 = (j0 + 16 + j_l) <= ig + 16;
#pragma unroll
      for (int g = 0; g < 16; ++g) {
        float m0 = 0.f, m1 = 0.f;
#pragma unroll
        for (int h = 0; h < 16; ++h) {
          float wv = sWpre[(g << 4) + h];
          m0 += wv * ch0[h];
          m1 += wv * ch1[h];
        }
        float e0 = ok0 ? __expf(m0 - 20.f) : 0.f;
        float e1 = ok1 ? __expf(m1 - 20.f) : 0.f;
        partL[g] += e0 + e1;
      }
    }
    __syncthreads();   // sS reads done before next iteration's QK writes
    ++uoff;
    if (uoff == ((it + 1) >> 1) + 1) {
      // flush L: thread's rows i = i0 + w*4 + quad; reduce over 16 m-lanes
#pragma unroll
      for (int g = 0; g < 16; ++g) {
        float v = partL[g];
        v += __shfl_xor(v, 1); v += __shfl_xor(v, 2);
        v += __shfl_xor(v, 4); v += __shfl_xor(v, 8);
        if (m == 0)
          atomicAdd(&Lbuf[(((size_t)(b << 10) + i0 + (w << 2) + quad) << 4) + g], v);
      }
      ++bi; b = bi >> 6; it = bi & 63; uoff = 0; fresh = true;
    }
  }
  if (!fresh) {
    const int i0 = it << 4;
#pragma unroll
    for (int g = 0; g < 16; ++g) {
      float v = partL[g];
      v += __shfl_xor(v, 1); v += __shfl_xor(v, 2);
      v += __shfl_xor(v, 4); v += __shfl_xor(v, 8);
      if (m == 0)
        atomicAdd(&Lbuf[(((size_t)(b << 10) + i0 + (w << 2) + quad) << 4) + g], v);
    }
  }
}

// ---- pass 2: recompute, normalize, W_post per column, PV with v[g2] --------
__global__ __launch_bounds__(256)
void attn_pv2(const unsigned short* __restrict__ qb, const unsigned short* __restrict__ kall,
              const unsigned short* __restrict__ vallT, const float* __restrict__ W_pre,
              const float* __restrict__ W_post, const float* __restrict__ Lbuf,
              float* __restrict__ Obuf)
{
  __shared__ float sS[16 * 16 * 33];            // [h][i][j 0..31]
  __shared__ unsigned short sE[16 * 16 * 40];   // bf16 p2 [g2][i][k 0..31 +8 pad]
  __shared__ float sWpre[256], sWpost[256], sIL[256];

  const int t = threadIdx.x, lane = t & 63, w = t >> 6;
  const int m = lane & 15, quad = lane >> 4;
  sWpre[t] = W_pre[t];
  sWpost[t] = W_post[t];

  const int blk = blockIdx.x;                   // grid 512
  const int u0 = (4352 * blk) >> 9, u1 = (4352 * (blk + 1)) >> 9;
  if (u0 == u1) return;

  int accu = 0, bi = 0;
  while (true) {
    int un = (((bi & 63) + 1) >> 1) + 1;
    if (accu + un > u0) break;
    accu += un; ++bi;
  }
  int b = bi >> 6, it = bi & 63, uoff = u0 - accu;

  short8 afr[4][2];
  f32x4 oacc[4][4];
  bool fresh = true;

  for (int u = u0; u < u1; ++u) {
    const int i0 = it << 4;
    if (fresh) {
#pragma unroll
      for (int hh = 0; hh < 4; ++hh)
#pragma unroll
        for (int kk = 0; kk < 2; ++kk)
          afr[hh][kk] = *(const short8*)(qb + (((size_t)(b << 10) + i0 + m) << 10)
                                         + ((w << 2) + hh) * 64 + kk * 32 + quad * 8);
#pragma unroll
      for (int a = 0; a < 4; ++a)
#pragma unroll
        for (int dt = 0; dt < 4; ++dt) oacc[a][dt] = (f32x4){0.f, 0.f, 0.f, 0.f};
      sIL[t] = 1.f / Lbuf[(((size_t)(b << 10) + i0 + (t >> 4)) << 4) + (t & 15)];
      fresh = false;
    }
    const int j0 = uoff << 5;
    // ---- QK: both 16-j subtiles -> sS ----
#pragma unroll
    for (int sub = 0; sub < 2; ++sub) {
      const int js = j0 + (sub << 4);
#pragma unroll
      for (int hh = 0; hh < 4; ++hh) {
        f32x4 s = (f32x4){0.f, 0.f, 0.f, 0.f};
#pragma unroll
        for (int kk = 0; kk < 2; ++kk) {
          short8 bfr = *(const short8*)(kall + ((size_t)(b * 1056 + js + m) << 10)
                                        + ((w << 2) + hh) * 64 + kk * 32 + quad * 8);
          s = __builtin_amdgcn_mfma_f32_16x16x32_bf16(afr[hh][kk], bfr, s, 0, 0, 0);
        }
#pragma unroll
        for (int reg = 0; reg < 4; ++reg)
          sS[(((w << 2) + hh) * 16 + (quad << 2) + reg) * 33 + (sub << 4) + m] = s[reg];
      }
    }
    __syncthreads();   // also covers sIL write at fresh
    // ---- premix + exp + normalize + W_post mix -> p2 (bf16, A-layout) ----
    {
      const int i_l = t >> 4, j_l = t & 15;
      const int ig = i0 + i_l;
      float ch0[16], ch1[16];
#pragma unroll
      for (int h = 0; h < 16; ++h) {
        ch0[h] = sS[(h * 16 + i_l) * 33 + j_l];
        ch1[h] = sS[(h * 16 + i_l) * 33 + 16 + j_l];
      }
      const bool ok0 = (j0 + j_l) <= ig + 16;
      const bool ok1 = (j0 + 16 + j_l) <= ig + 16;
      float e0[16], e1[16];
#pragma unroll
      for (int g = 0; g < 16; ++g) {
        float m0 = 0.f, m1 = 0.f;
#pragma unroll
        for (int h = 0; h < 16; ++h) {
          float wv = sWpre[(g << 4) + h];
          m0 += wv * ch0[h];
          m1 += wv * ch1[h];
        }
        float il = sIL[(i_l << 4) + g];
        e0[g] = ok0 ? __expf(m0 - 20.f) * il : 0.f;
        e1[g] = ok1 ? __expf(m1 - 20.f) * il : 0.f;
      }
#pragma unroll
      for (int g2 = 0; g2 < 16; ++g2) {
        float p0 = 0.f, p1 = 0.f;
#pragma unroll
        for (int g = 0; g < 16; ++g) {
          float wv = sWpost[(g2 << 4) + g];
          p0 += wv * e0[g];
          p1 += wv * e1[g];
        }
        sE[(g2 * 16 + i_l) * 40 + j_l] = to_bf(p0);
        sE[(g2 * 16 + i_l) * 40 + 16 + j_l] = to_bf(p1);
      }
    }
    __syncthreads();
    // ---- PV: wave w owns g2 = 4w..4w+3; V indexed by g2 (output head) ----
#pragma unroll
    for (int gl = 0; gl < 4; ++gl) {
      const int g2 = (w << 2) + gl;
      short8 a = *(const short8*)((const char*)sE + ((g2 * 16 + m) * 40 + quad * 8) * 2);
#pragma unroll
      for (int dt = 0; dt < 4; ++dt) {
        short8 bv = *(const short8*)(vallT + ((size_t)((b << 10) + g2 * 64 + dt * 16 + m)) * 1056
                                     + j0 + quad * 8);
        oacc[gl][dt] = __builtin_amdgcn_mfma_f32_16x16x32_bf16(a, bv, oacc[gl][dt], 0, 0, 0);
      }
    }
    // ---- advance / flush on it-boundary ----
    ++uoff;
    if (uoff == ((it + 1) >> 1) + 1) {
#pragma unroll
      for (int gl = 0; gl < 4; ++gl) {
        int g2 = (w << 2) + gl;
#pragma unroll
        for (int dt = 0; dt < 4; ++dt)
#pragma unroll
          for (int reg = 0; reg < 4; ++reg)
            atomicAdd(&Obuf[(((size_t)(b << 10) + i0 + (quad << 2) + reg) << 10)
                            + g2 * 64 + dt * 16 + m], oacc[gl][dt][reg]);
      }
      ++bi; b = bi >> 6; it = bi & 63; uoff = 0; fresh = true;
    }
  }
  if (!fresh) {
    const int i0 = it << 4;
#pragma unroll
    for (int gl = 0; gl < 4; ++gl) {
      int g2 = (w << 2) + gl;
#pragma unroll
      for (int dt = 0; dt < 4; ++dt)
#pragma unroll
        for (int reg = 0; reg < 4; ++reg)
          atomicAdd(&Obuf[(((size_t)(b << 10) + i0 + (quad << 2) + reg) << 10)
                          + g2 * 64 + dt * 16 + m], oacc[gl][dt][reg]);
    }
  }
}

// ---- epilogue: aob = Obuf * hgate * vgate (bf16) ---------------------------
__global__ __launch_bounds__(256)
void gate_out(const float* __restrict__ Obuf, const float* __restrict__ hgate,
              const float* __restrict__ vgate, unsigned short* __restrict__ aob)
{
  int i4 = blockIdx.x * 256 + threadIdx.x;   // 1048576 float4 groups
  float4 o = ((const float4*)Obuf)[i4];
  int base = i4 << 2;
  int row = base >> 10, hd = base & 1023, h = hd >> 6;
  float hg = hgate[(row << 4) + h];
  float4 vg = ((const float4*)vgate)[i4];
  ushort4 r;
  r.x = to_bf(o.x * hg * vg.x);
  r.y = to_bf(o.y * hg * vg.y);
  r.z = to_bf(o.z * hg * vg.z);
  r.w = to_bf(o.w * hg * vg.w);
  ((ushort4*)aob)[i4] = r;
}

extern "C" void kernel_launch(void* const* d_in, const int* in_sizes, int n_in,
                              void* d_out, int out_size, void* d_ws, size_t ws_size,
                              hipStream_t stream)
{
  const float* x       = (const float*)d_in[0];
  const float* freqs   = (const float*)d_in[1];
  const float* Wq      = (const float*)d_in[2];
  const float* Wk      = (const float*)d_in[3];
  const float* Wv      = (const float*)d_in[4];
  const float* q_scale = (const float*)d_in[5];
  const float* k_scale = (const float*)d_in[6];
  const float* mem_k   = (const float*)d_in[7];
  const float* mem_v   = (const float*)d_in[8];
  const float* W_pre   = (const float*)d_in[9];
  const float* W_post  = (const float*)d_in[10];
  const float* W_hg    = (const float*)d_in[11];
  const float* b_hg    = (const float*)d_in[12];
  const float* W_vg    = (const float*)d_in[13];
  const float* b_vg    = (const float*)d_in[14];
  const float* Wo      = (const float*)d_in[15];
  float* out = (float*)d_out;
  float* ws  = (float*)d_ws;

  // workspace (float offsets), non-overlapping; total 19,660,800 f = 78.6 MiB
  float* q_lin = ws;                                        // [4096,1024]; dead -> aob
  unsigned short* aob = (unsigned short*)ws;
  float* k_lin = ws + 4194304;                              // [4096,1024]; dead -> Obuf
  float* Obuf  = k_lin;                                     // [4,1024,16,64] fp32
  float* vgbuf = ws + 8388608;                              // [4096,1024]
  float* hgbuf = ws + 12582912;                             // [4096,16]
  float* Lbuf  = ws + 12648448;                             // [4,1024,16]
  unsigned short* xb   = (unsigned short*)(ws + 12713984);  // [4096,1024] bf16 -> qb; ends 14,811,136
  unsigned short* qb   = xb;
  unsigned short* kall = (unsigned short*)(ws + 14811136);  // [4,1056,1024] bf16; ends 16,973,824
  unsigned short* vallT= (unsigned short*)(ws + 16973824);  // [4,1024,1056] bf16; ends 19,136,512
  unsigned short* wb   = (unsigned short*)(ws + 19136512);  // [1024,1024] bf16 (reused)

  dim3 blk(256);
  cvt_bf16x4<<<4096, blk, 0, stream>>>(x, xb, 1048576);
  // head-gate projection (fp32, reads original x)
  gemm_f32<<<dim3(1, 64), blk, 0, stream>>>(x, W_hg, hgbuf, 4096, 16, 1024);
  sigmoid_bias<<<256, blk, 0, stream>>>(hgbuf, b_hg, 65536, 15);
  // MFMA projections, 128x128 tiles (weight transpose buffer reused serially)
  transpose_to_bf<<<dim3(16, 16), blk, 0, stream>>>(Wq, wb);
  gemm_bf128<<<dim3(8, 32), blk, 0, stream>>>(xb, wb, q_lin, nullptr, 0);
  transpose_to_bf<<<dim3(16, 16), blk, 0, stream>>>(Wk, wb);
  gemm_bf128<<<dim3(8, 32), blk, 0, stream>>>(xb, wb, k_lin, nullptr, 0);
  transpose_to_bf<<<dim3(16, 16), blk, 0, stream>>>(Wv, wb);
  gemm_bf128<<<dim3(8, 32), blk, 0, stream>>>(xb, wb, nullptr, vallT, 1);
  transpose_to_bf<<<dim3(16, 16), blk, 0, stream>>>(W_vg, wb);
  gemm_bf128<<<dim3(8, 32), blk, 0, stream>>>(xb, wb, vgbuf, nullptr, 0);
  sigmoid_bias<<<16384, blk, 0, stream>>>(vgbuf, b_vg, 4194304, 1023);
  // q/k/mem postprocessing (qb overwrites xb -- all xb readers done)
  q_post_bf<<<16384, blk, 0, stream>>>(q_lin, q_scale, freqs, qb);
  k_post_bf<<<16384, blk, 0, stream>>>(k_lin, k_scale, freqs, kall);
  mem_build<<<64, blk, 0, stream>>>(mem_k, mem_v, k_scale, kall, vallT);
  // zero accumulators (k_lin dead after k_post_bf -> Obuf alias)
  hipMemsetAsync(Lbuf, 0, 65536 * sizeof(float), stream);
  hipMemsetAsync(Obuf, 0, 4194304 * sizeof(float), stream);
  // two-pass attention + gate epilogue
  attn_lsum<<<1024, blk, 0, stream>>>(qb, kall, W_pre, Lbuf);
  attn_pv2<<<512, blk, 0, stream>>>(qb, kall, vallT, W_pre, W_post, Lbuf, Obuf);
  gate_out<<<4096, blk, 0, stream>>>(Obuf, hgbuf, vgbuf, aob);
  // output projection
  transpose_to_bf<<<dim3(16, 16), blk, 0, stream>>>(Wo, wb);
  gemm_bf128<<<dim3(8, 32), blk, 0, stream>>>(aob, wb, out, nullptr, 0);
}